// Round 3
// baseline (19599.124 us; speedup 1.0000x reference)
//
#include <hip/hip_runtime.h>
#include <hip/hip_bf16.h>

// SNN, 5 layers, T=100, B=512.
// R3 structure:
//  - split_weights: W_h -> 3 bf16 planes per layer, MFMA-B-tiled (R2-verified).
//  - pre_gemm0: Z0[t] = data[t] @ W_in^T + b_in for a chunk of T steps (fp32,
//    layer 0 has no recurrence in z -> off the serial path), output MFMA-tiled.
//  - snn_persistent: ONE kernel per chunk, 256 blocks (1/CU), runs the whole
//    serial chain with hand-rolled grid barriers. 3 syncs/step:
//      P1: L1(t) MFMA  (+ out(t-1) on the side)
//      P2: L2(t) MFMA
//      P3: L3(t) MFMA + leaky0(t+1) elementwise from Z0
//    Hidden weights stay XCD-L2-resident (n-tile <-> XCD affinity).

#define NB 512
#define NH 1024
#define NI 512
#define NO 35
#define TT 100
#define NBLK 256
#define MAXPH 384

typedef __bf16 bf16x8 __attribute__((ext_vector_type(8)));
typedef float f32x4 __attribute__((ext_vector_type(4)));

// MFMA 16x16x32 operand tiling over [rows][K]: [row/16][k/32][lane][8],
// lane = (row&15) | (((k>>3)&3)<<4), elem j = k&7.  (R2-verified.)
__device__ __forceinline__ size_t tiled_off(int row, int k) {
    return ((size_t)((row >> 4) * 32 + (k >> 5)) * 64
            + (row & 15) + (((k >> 3) & 3) << 4)) * 8 + (k & 7);
}

__device__ __forceinline__ void leaky_upd(float zin, float mprev, float be, float th,
                                          float& mnew, float& spk) {
    float rs = (mprev - th > 0.0f) ? th : 0.0f;          // reset*thr (detached)
    float bc = fminf(fmaxf(be, 0.0f), 1.0f);             // clip(beta,0,1)
    mnew = bc * mprev + zin - rs;
    spk  = (mnew - th > 0.0f) ? 1.0f : 0.0f;
}

// ---------------- weight split: W_h[3][NH][NH] fp32 -> 3 bf16 planes, tiled --
__global__ __launch_bounds__(256)
void split_weights(const float* __restrict__ W_h, __bf16* __restrict__ Wt) {
    const int id = blockIdx.x * 256 + threadIdx.x;   // 3 * 1024 * 128
    const int layer = id >> 17;
    const int rem = id & 131071;
    const int n = rem >> 7;
    const int k0 = (rem & 127) << 3;
    const float* src = W_h + ((size_t)layer * NH + n) * NH + k0;
    __bf16* dst = Wt + (size_t)layer * 3 * NH * NH;
    const size_t PS = (size_t)NH * NH;
    const size_t off = tiled_off(n, k0);
    bf16x8 p1, p2, p3;
    #pragma unroll
    for (int j = 0; j < 8; ++j) {
        float w = src[j];
        __bf16 a = (__bf16)w;  float r1 = w - (float)a;
        __bf16 b = (__bf16)r1; float r2 = r1 - (float)b;
        __bf16 c = (__bf16)r2;
        p1[j] = a; p2[j] = b; p3[j] = c;
    }
    *reinterpret_cast<bf16x8*>(dst + 0 * PS + off) = p1;
    *reinterpret_cast<bf16x8*>(dst + 1 * PS + off) = p2;
    *reinterpret_cast<bf16x8*>(dst + 2 * PS + off) = p3;
}

// ---------------- pre-GEMM: Z0 = X @ W_in^T + b_in, tiled fp32 output -------
#define BM 32
#define BN 64
#define BK 32

__global__ __launch_bounds__(256)
void pre_gemm0(const float* __restrict__ X,     // rows of [tc*NB][NI]
               const float* __restrict__ W,     // [NH][NI]
               const float* __restrict__ bias,  // [NH]
               float* __restrict__ Z0)          // [tc][NB*NH tiled] fp32
{
    __shared__ float Xs[BK][BM + 2];
    __shared__ float Ws[BK][BN + 4];

    const int tid = threadIdx.x;
    const int tx  = tid & 15;
    const int ty  = tid >> 4;
    const int n0  = blockIdx.x * BN;
    const int r0  = blockIdx.y * BM;   // row within chunk

    float acc[2][4] = {{0.f,0.f,0.f,0.f},{0.f,0.f,0.f,0.f}};

    const int lr = tid >> 3;
    const int lc = (tid & 7) * 4;

    for (int kk = 0; kk < NI; kk += BK) {
        {
            float4 v = *reinterpret_cast<const float4*>(&X[(size_t)(r0 + lr) * NI + kk + lc]);
            Xs[lc + 0][lr] = v.x; Xs[lc + 1][lr] = v.y;
            Xs[lc + 2][lr] = v.z; Xs[lc + 3][lr] = v.w;
        }
        #pragma unroll
        for (int h = 0; h < 2; ++h) {
            int n = lr + h * 32;
            float4 v = *reinterpret_cast<const float4*>(&W[(size_t)(n0 + n) * NI + kk + lc]);
            Ws[lc + 0][n] = v.x; Ws[lc + 1][n] = v.y;
            Ws[lc + 2][n] = v.z; Ws[lc + 3][n] = v.w;
        }
        __syncthreads();

        #pragma unroll
        for (int k = 0; k < BK; ++k) {
            float2 xv = *reinterpret_cast<const float2*>(&Xs[k][ty * 2]);
            float4 wv = *reinterpret_cast<const float4*>(&Ws[k][tx * 4]);
            acc[0][0] += xv.x * wv.x; acc[0][1] += xv.x * wv.y;
            acc[0][2] += xv.x * wv.z; acc[0][3] += xv.x * wv.w;
            acc[1][0] += xv.y * wv.x; acc[1][1] += xv.y * wv.y;
            acc[1][2] += xv.y * wv.z; acc[1][3] += xv.y * wv.w;
        }
        __syncthreads();
    }

    const int nidx = n0 + tx * 4;
    float4 biv = *reinterpret_cast<const float4*>(&bias[nidx]);

    #pragma unroll
    for (int i = 0; i < 2; ++i) {
        const int row = r0 + ty * 2 + i;
        const int t_loc = row >> 9;
        const int b = row & 511;
        float4 z;
        z.x = acc[i][0] + biv.x; z.y = acc[i][1] + biv.y;
        z.z = acc[i][2] + biv.z; z.w = acc[i][3] + biv.w;
        *reinterpret_cast<float4*>(&Z0[(size_t)t_loc * (NB * NH) + tiled_off(b, nidx)]) = z;
    }
}

// ---------------- grid barrier (two-level, fresh counters per phase) --------
__device__ __forceinline__ void gridbar(int* cnt, int* root, int* gen, int phase) {
    __syncthreads();
    if (threadIdx.x == 0) {
        const int g = phase + 1;
        if (__hip_atomic_fetch_add(&cnt[phase * 8 + (blockIdx.x & 7)], 1,
                                   __ATOMIC_ACQ_REL, __HIP_MEMORY_SCOPE_AGENT) == 31) {
            if (__hip_atomic_fetch_add(&root[phase], 1,
                                       __ATOMIC_ACQ_REL, __HIP_MEMORY_SCOPE_AGENT) == 7) {
                __hip_atomic_store(gen, g, __ATOMIC_RELEASE, __HIP_MEMORY_SCOPE_AGENT);
            }
        }
        while (__hip_atomic_load(gen, __ATOMIC_ACQUIRE, __HIP_MEMORY_SCOPE_AGENT) < g) {
            __builtin_amdgcn_s_sleep(2);
        }
    }
    __syncthreads();
}

// ---------------- per-phase device functions --------------------------------
__device__ __forceinline__ void hidden_phase(const __bf16* __restrict__ Xt,
                                             const __bf16* __restrict__ Wp,
                                             const float* __restrict__ bias,
                                             float* __restrict__ mem,
                                             const float* __restrict__ beta,
                                             const float* __restrict__ thr,
                                             __bf16* __restrict__ Yt,
                                             int m_t, int n_t) {
    const int tid  = threadIdx.x;
    const int lane = tid & 63;
    const int w    = tid >> 6;
    const int wm   = w >> 1, wn = w & 1;
    const int mt0  = m_t * 2 + wm;          // 16-row A tile
    const int ntA  = n_t * 4 + wn * 2;      // two 16-col B tiles
    const size_t PS = (size_t)NH * NH;

    f32x4 acc0 = {}, acc1 = {};

    for (int kt = 0; kt < 32; ++kt) {
        bf16x8 a = *reinterpret_cast<const bf16x8*>(Xt + ((size_t)(mt0 * 32 + kt) * 64 + lane) * 8);
        #pragma unroll
        for (int p = 0; p < 3; ++p) {
            bf16x8 b0 = *reinterpret_cast<const bf16x8*>(Wp + p * PS + ((size_t)(ntA * 32 + kt) * 64 + lane) * 8);
            bf16x8 b1 = *reinterpret_cast<const bf16x8*>(Wp + p * PS + ((size_t)((ntA + 1) * 32 + kt) * 64 + lane) * 8);
            acc0 = __builtin_amdgcn_mfma_f32_16x16x32_bf16(a, b0, acc0, 0, 0, 0);
            acc1 = __builtin_amdgcn_mfma_f32_16x16x32_bf16(a, b1, acc1, 0, 0, 0);
        }
    }

    const int r0 = (lane >> 4) * 4;
    const int c  = lane & 15;
    const int b_base = m_t * 32 + wm * 16;
    #pragma unroll
    for (int ni = 0; ni < 2; ++ni) {
        const int n = n_t * 64 + wn * 32 + ni * 16 + c;
        const float bi = bias[n], be = beta[n], th = thr[n];
        f32x4 A = ni ? acc1 : acc0;
        #pragma unroll
        for (int r = 0; r < 4; ++r) {
            const int b = b_base + r0 + r;
            float mp = mem[(size_t)b * NH + n];
            float mn, sp;
            leaky_upd(A[r] + bi, mp, be, th, mn, sp);
            mem[(size_t)b * NH + n] = mn;
            Yt[tiled_off(b, n)] = (__bf16)sp;
        }
    }
}

__device__ __forceinline__ void leaky0_phase(const float* __restrict__ Z0,
                                             float* __restrict__ mem0t,
                                             __bf16* __restrict__ spk0,
                                             const float* __restrict__ beta0,
                                             const float* __restrict__ thr0,
                                             int s_loc) {
    const size_t i0 = (size_t)blockIdx.x * 2048 + (size_t)threadIdx.x * 8;
    const float* zp = Z0 + (size_t)s_loc * (NB * NH) + i0;
    float* mp = mem0t + i0;
    // neuron index for 8 consecutive tiled elems: n = kt*32 + lanehi*8 + j
    const int n8 = ((((int)(i0 >> 9)) & 31) << 5) + ((((int)(i0 >> 7)) & 3) << 3);

    float4 za = *reinterpret_cast<const float4*>(zp);
    float4 zb = *reinterpret_cast<const float4*>(zp + 4);
    float4 ma = *reinterpret_cast<const float4*>(mp);
    float4 mb = *reinterpret_cast<const float4*>(mp + 4);
    float4 e0 = *reinterpret_cast<const float4*>(&beta0[n8]);
    float4 e1 = *reinterpret_cast<const float4*>(&beta0[n8 + 4]);
    float4 h0 = *reinterpret_cast<const float4*>(&thr0[n8]);
    float4 h1 = *reinterpret_cast<const float4*>(&thr0[n8 + 4]);

    bf16x8 s;
    float mn, sp;
    leaky_upd(za.x, ma.x, e0.x, h0.x, mn, sp); ma.x = mn; s[0] = (__bf16)sp;
    leaky_upd(za.y, ma.y, e0.y, h0.y, mn, sp); ma.y = mn; s[1] = (__bf16)sp;
    leaky_upd(za.z, ma.z, e0.z, h0.z, mn, sp); ma.z = mn; s[2] = (__bf16)sp;
    leaky_upd(za.w, ma.w, e0.w, h0.w, mn, sp); ma.w = mn; s[3] = (__bf16)sp;
    leaky_upd(zb.x, mb.x, e1.x, h1.x, mn, sp); mb.x = mn; s[4] = (__bf16)sp;
    leaky_upd(zb.y, mb.y, e1.y, h1.y, mn, sp); mb.y = mn; s[5] = (__bf16)sp;
    leaky_upd(zb.z, mb.z, e1.z, h1.z, mn, sp); mb.z = mn; s[6] = (__bf16)sp;
    leaky_upd(zb.w, mb.w, e1.w, h1.w, mn, sp); mb.w = mn; s[7] = (__bf16)sp;

    *reinterpret_cast<float4*>(mp)     = ma;
    *reinterpret_cast<float4*>(mp + 4) = mb;
    *reinterpret_cast<bf16x8*>(spk0 + i0) = s;
}

__device__ __forceinline__ void out_phase(const __bf16* __restrict__ spk3,
                                          const float* __restrict__ W,
                                          const float* __restrict__ bias,
                                          float* __restrict__ memo,
                                          const float* __restrict__ beta,
                                          const float* __restrict__ thr,
                                          float* __restrict__ outt) {
    const int tid = threadIdx.x;
    if (tid >= 70) return;
    const int r = (tid >= 35) ? 1 : 0;
    const int o = tid - r * 35;
    const int b = blockIdx.x * 2 + r;

    const float* wr = W + (size_t)o * NH;
    float acc = 0.0f;
    for (int k0 = 0; k0 < NH; k0 += 8) {
        const bf16x8 xv = *reinterpret_cast<const bf16x8*>(spk3 + tiled_off(b, k0));
        float4 w0 = *reinterpret_cast<const float4*>(wr + k0);
        float4 w1 = *reinterpret_cast<const float4*>(wr + k0 + 4);
        acc += (float)xv[0] * w0.x + (float)xv[1] * w0.y
             + (float)xv[2] * w0.z + (float)xv[3] * w0.w
             + (float)xv[4] * w1.x + (float)xv[5] * w1.y
             + (float)xv[6] * w1.z + (float)xv[7] * w1.w;
    }
    acc += bias[o];

    float mp = memo[b * NO + o];
    float mn, sp;
    leaky_upd(acc, mp, beta[o], thr[o], mn, sp);
    memo[b * NO + o] = mn;
    outt[b * NO + o] = sp;
}

// ---------------- the persistent serial kernel ------------------------------
__global__ __launch_bounds__(256, 1)
void snn_persistent(const float* __restrict__ Z0,
                    const __bf16* __restrict__ Wt,
                    const float* __restrict__ b_h,
                    const float* __restrict__ W_out,
                    const float* __restrict__ b_out,
                    const float* __restrict__ beta_h,
                    const float* __restrict__ thr_h,
                    const float* __restrict__ beta_o,
                    const float* __restrict__ thr_o,
                    float* __restrict__ mem_h,   // [0]: layer0 tiled, [1..3] row-major
                    float* __restrict__ mem_o,
                    __bf16* __restrict__ spk0, __bf16* __restrict__ spk1,
                    __bf16* __restrict__ spk2, __bf16* __restrict__ spk3,
                    float* __restrict__ out,
                    int* __restrict__ cnt, int* __restrict__ root, int* __restrict__ gen,
                    int t0, int tc, int last)
{
    const int blk = blockIdx.x;
    // XCD-affine tile map: blocks on the same XCD (blk%8) share n-tiles.
    const int n_t = (blk & 7) * 2 + ((blk >> 3) & 1);   // 0..15 (64 neurons)
    const int m_t = blk >> 4;                            // 0..15 (32 rows)
    const size_t PS3 = (size_t)3 * NH * NH;
    float* mem0t = mem_h;                                // tiled-linear fp32
    int phase = 0;

    leaky0_phase(Z0, mem0t, spk0, beta_h, thr_h, 0);
    gridbar(cnt, root, gen, phase++);

    for (int s = 0; s < tc; ++s) {
        const int t = t0 + s;
        hidden_phase(spk0, Wt + 0 * PS3, b_h + 0 * NH, mem_h + 1 * (size_t)NB * NH,
                     beta_h + 1 * NH, thr_h + 1 * NH, spk1, m_t, n_t);
        if (t > 0)
            out_phase(spk3, W_out, b_out, mem_o, beta_o, thr_o,
                      out + (size_t)(t - 1) * NB * NO);
        gridbar(cnt, root, gen, phase++);

        hidden_phase(spk1, Wt + 1 * PS3, b_h + 1 * NH, mem_h + 2 * (size_t)NB * NH,
                     beta_h + 2 * NH, thr_h + 2 * NH, spk2, m_t, n_t);
        gridbar(cnt, root, gen, phase++);

        hidden_phase(spk2, Wt + 2 * PS3, b_h + 2 * NH, mem_h + 3 * (size_t)NB * NH,
                     beta_h + 3 * NH, thr_h + 3 * NH, spk3, m_t, n_t);
        if (s + 1 < tc)
            leaky0_phase(Z0, mem0t, spk0, beta_h, thr_h, s + 1);
        gridbar(cnt, root, gen, phase++);
    }

    if (last)
        out_phase(spk3, W_out, b_out, mem_o, beta_o, thr_o,
                  out + (size_t)(t0 + tc - 1) * NB * NO);
}

// ---------------- launch ----------------------------------------------------
extern "C" void kernel_launch(void* const* d_in, const int* in_sizes, int n_in,
                              void* d_out, int out_size, void* d_ws, size_t ws_size,
                              hipStream_t stream) {
    const float* data   = (const float*)d_in[0];
    const float* W_in   = (const float*)d_in[1];
    const float* b_in   = (const float*)d_in[2];
    const float* W_h    = (const float*)d_in[3];
    const float* b_h    = (const float*)d_in[4];
    const float* W_out  = (const float*)d_in[5];
    const float* b_out  = (const float*)d_in[6];
    const float* beta_h = (const float*)d_in[7];
    const float* thr_h  = (const float*)d_in[8];
    const float* beta_o = (const float*)d_in[9];
    const float* thr_o  = (const float*)d_in[10];
    float* out = (float*)d_out;

    char* ws = (char*)d_ws;
    float*  mem_h = (float*)(ws + 0);                    //  8,388,608 B
    float*  mem_o = (float*)(ws + 8388608);              //     71,680 B
    __bf16* spk0  = (__bf16*)(ws + 8460288);             //  1,048,576 B
    __bf16* spk1  = (__bf16*)(ws + 9508864);
    __bf16* spk2  = (__bf16*)(ws + 10557440);
    __bf16* spk3  = (__bf16*)(ws + 11606016);
    __bf16* Wt    = (__bf16*)(ws + 12654592);            // 18,874,368 B
    int*    cnt   = (int*)(ws + 31528960);               // MAXPH*8*4 = 12,288 B
    int*    root  = (int*)(ws + 31541248);               // MAXPH*4   =  1,536 B
    int*    gen   = (int*)(ws + 31542784);               // 64 B (padded)
    float*  Z0    = (float*)(ws + 31542848);             // Tc * 2 MB

    const size_t FIXED = 31542848;
    const size_t STEPB = (size_t)NB * NH * sizeof(float);   // 2 MB
    size_t avail = (ws_size > FIXED) ? (ws_size - FIXED) / STEPB : 1;
    int Tc = (int)(avail < 1 ? 1 : (avail > TT ? TT : avail));

    hipMemsetAsync(mem_h, 0, 8460288, stream);
    split_weights<<<dim3(1536), dim3(256), 0, stream>>>(W_h, Wt);

    for (int t0c = 0; t0c < TT; t0c += Tc) {
        const int tcc = (TT - t0c < Tc) ? (TT - t0c) : Tc;
        pre_gemm0<<<dim3(NH / BN, tcc * (NB / BM)), dim3(256), 0, stream>>>(
            data + (size_t)t0c * NB * NI, W_in, b_in, Z0);
        hipMemsetAsync(cnt, 0, 13888, stream);   // cnt + root + gen
        snn_persistent<<<dim3(NBLK), dim3(256), 0, stream>>>(
            Z0, Wt, b_h, W_out, b_out, beta_h, thr_h, beta_o, thr_o,
            mem_h, mem_o, spk0, spk1, spk2, spk3, out,
            cnt, root, gen, t0c, tcc, (t0c + tcc == TT) ? 1 : 0);
    }
}

// Round 5
// 6251.961 us; speedup vs baseline: 3.1349x; 3.1349x over previous
//
#include <hip/hip_runtime.h>
#include <hip/hip_bf16.h>

// SNN, 5 layers, T=100, B=512.  R5 = R4 with the fence builtin fixed
// (__hip_atomic_fence -> __builtin_amdgcn_fence).
//  - split_weights / split_win / split_wout: fp32 -> 3 bf16 planes, MFMA-tiled.
//  - z0_gemm: Z0 = data @ W_in^T + b_in via 6-cross-term bf16 MFMA (data split
//    on the fly), residual ~2^-24 << fp32 reorder noise. All T upfront.
//  - snn_pipe: 256 persistent blocks (1/CU), skewed time pipeline:
//      phase p: L1(t=p-1) | L2(t=p-2) | L3(t=p-3) | out(t=p-4) | leaky0(t=p)
//    Hidden blocks: 16-neuron slice, weight planes 1+2 in LDS (64KB, immune to
//    the per-barrier L2 invalidate), plane 3 streamed. ~104 grid barriers with
//    relaxed flag stores + leader scan (no serialized agent RMW, no per-poll
//    acquire-invalidate).

#define NB 512
#define NH 1024
#define NI 512
#define NO 35
#define TT 100
#define NBLK 256

typedef __bf16 bf16x8 __attribute__((ext_vector_type(8)));
typedef float f32x4 __attribute__((ext_vector_type(4)));

// MFMA 16x16x32 operand tiling over [rows][K]: [row/16][k/32][lane][8],
// lane = (row&15) | (((k>>3)&3)<<4), elem j = k&7.  KT = K/32.
__device__ __forceinline__ size_t tiled_off(int row, int k, int KT) {
    return ((size_t)((row >> 4) * KT + (k >> 5)) * 64
            + (row & 15) + (((k >> 3) & 3) << 4)) * 8 + (k & 7);
}

__device__ __forceinline__ void leaky_upd(float zin, float mprev, float be, float th,
                                          float& mnew, float& spk) {
    float rs = (mprev - th > 0.0f) ? th : 0.0f;          // reset*thr (detached)
    float bc = fminf(fmaxf(be, 0.0f), 1.0f);             // clip(beta,0,1)
    mnew = bc * mprev + zin - rs;
    spk  = (mnew - th > 0.0f) ? 1.0f : 0.0f;
}

// ---------------- ws layout (bytes) ----------------
#define WS_MEM0     0u           // 2,097,152  (layer-0 mem, tiled-linear fp32)
#define WS_MEM123   2097152u     // 6,291,456  (mem for L1..L3, row-major)
#define WS_MEMO     8388608u     // 98,304     (output mem [512][35])
#define WS_FLAGS    8486912u     // 1,024      (256 ints)
#define WS_GEN      8487936u     // 256
#define WS_SPK0     8488192u     // 2 x 1,048,576 (ring)
#define WS_SPK1     10585344u
#define WS_SPK2     12682496u
#define WS_SPK3     14779648u
#define WS_WT       16876800u    // 18,874,368 (W_h: 3 layers x 3 planes, tiled)
#define WS_WIT      35751168u    // 3,145,728  (W_in: 3 planes, tiled KT=16)
#define WS_WOT      38896896u    // 294,912    (W_out padded to 48 rows, 3 planes)
#define WS_Z0       39191808u    // Tc x 2 MB fp32 (tiled)

// ---------------- weight splits ----------------
__global__ __launch_bounds__(256)
void split_weights(const float* __restrict__ W_h, __bf16* __restrict__ Wt) {
    const int id = blockIdx.x * 256 + threadIdx.x;   // 3 * 1024 * 128
    const int layer = id >> 17;
    const int rem = id & 131071;
    const int n = rem >> 7;
    const int k0 = (rem & 127) << 3;
    const float* src = W_h + ((size_t)layer * NH + n) * NH + k0;
    __bf16* dst = Wt + (size_t)layer * 3 * NH * NH;
    const size_t PS = (size_t)NH * NH;
    const size_t off = tiled_off(n, k0, 32);
    bf16x8 p1, p2, p3;
    #pragma unroll
    for (int j = 0; j < 8; ++j) {
        float w = src[j];
        __bf16 a = (__bf16)w;  float r1 = w - (float)a;
        __bf16 b = (__bf16)r1; float r2 = r1 - (float)b;
        __bf16 c = (__bf16)r2;
        p1[j] = a; p2[j] = b; p3[j] = c;
    }
    *reinterpret_cast<bf16x8*>(dst + 0 * PS + off) = p1;
    *reinterpret_cast<bf16x8*>(dst + 1 * PS + off) = p2;
    *reinterpret_cast<bf16x8*>(dst + 2 * PS + off) = p3;
}

__global__ __launch_bounds__(256)
void split_win(const float* __restrict__ W_in, __bf16* __restrict__ Wi_t) {
    const int id = blockIdx.x * 256 + threadIdx.x;   // 1024 * 64
    const int n = id >> 6;
    const int k0 = (id & 63) << 3;
    const float* src = W_in + (size_t)n * NI + k0;
    const size_t PS = (size_t)NH * NI;
    const size_t off = tiled_off(n, k0, 16);
    bf16x8 p1, p2, p3;
    #pragma unroll
    for (int j = 0; j < 8; ++j) {
        float w = src[j];
        __bf16 a = (__bf16)w;  float r1 = w - (float)a;
        __bf16 b = (__bf16)r1; float r2 = r1 - (float)b;
        __bf16 c = (__bf16)r2;
        p1[j] = a; p2[j] = b; p3[j] = c;
    }
    *reinterpret_cast<bf16x8*>(Wi_t + 0 * PS + off) = p1;
    *reinterpret_cast<bf16x8*>(Wi_t + 1 * PS + off) = p2;
    *reinterpret_cast<bf16x8*>(Wi_t + 2 * PS + off) = p3;
}

__global__ __launch_bounds__(256)
void split_wout(const float* __restrict__ W_out, __bf16* __restrict__ Wo_t) {
    const int id = blockIdx.x * 256 + threadIdx.x;   // 48 * 128
    if (id >= 48 * 128) return;
    const int o = id >> 7;
    const int k0 = (id & 127) << 3;
    const size_t PS = (size_t)48 * NH;
    const size_t off = tiled_off(o, k0, 32);
    bf16x8 p1 = {}, p2 = {}, p3 = {};
    if (o < NO) {
        const float* src = W_out + (size_t)o * NH + k0;
        #pragma unroll
        for (int j = 0; j < 8; ++j) {
            float w = src[j];
            __bf16 a = (__bf16)w;  float r1 = w - (float)a;
            __bf16 b = (__bf16)r1; float r2 = r1 - (float)b;
            __bf16 c = (__bf16)r2;
            p1[j] = a; p2[j] = b; p3[j] = c;
        }
    }
    *reinterpret_cast<bf16x8*>(Wo_t + 0 * PS + off) = p1;
    *reinterpret_cast<bf16x8*>(Wo_t + 1 * PS + off) = p2;
    *reinterpret_cast<bf16x8*>(Wo_t + 2 * PS + off) = p3;
}

// ---------------- Z0 = data @ W_in^T + b_in (6-term bf16 MFMA) --------------
__global__ __launch_bounds__(256)
void z0_gemm(const float* __restrict__ X,      // [Mrows][NI]
             const __bf16* __restrict__ Wi_t,  // 3 planes tiled KT=16
             const float* __restrict__ bias,
             float* __restrict__ Z0)           // [t][NB*NH] tiled fp32
{
    const int tid = threadIdx.x;
    const int lane = tid & 63;
    const int w = tid >> 6;
    const int wm = w >> 1, wn = w & 1;
    const int m_base = blockIdx.y * 64 + wm * 32;
    const int n_base = blockIdx.x * 64 + wn * 32;
    const size_t PS = (size_t)NH * NI;

    f32x4 acc[2][2] = {};
    bf16x8 a1[2], a2[2], a3[2];

    for (int kt = 0; kt < 16; ++kt) {
        #pragma unroll
        for (int mt = 0; mt < 2; ++mt) {
            const int row = m_base + mt * 16 + (lane & 15);
            const float* src = X + (size_t)row * NI + kt * 32 + ((lane >> 4) << 3);
            float4 v0 = *reinterpret_cast<const float4*>(src);
            float4 v1 = *reinterpret_cast<const float4*>(src + 4);
            float xv[8] = {v0.x, v0.y, v0.z, v0.w, v1.x, v1.y, v1.z, v1.w};
            #pragma unroll
            for (int j = 0; j < 8; ++j) {
                float x = xv[j];
                __bf16 h1 = (__bf16)x;  float r1 = x - (float)h1;
                __bf16 h2 = (__bf16)r1; float r2 = r1 - (float)h2;
                __bf16 h3 = (__bf16)r2;
                a1[mt][j] = h1; a2[mt][j] = h2; a3[mt][j] = h3;
            }
        }
        #pragma unroll
        for (int nt = 0; nt < 2; ++nt) {
            const size_t bo = ((size_t)(((n_base >> 4) + nt) * 16 + kt) * 64 + lane) * 8;
            bf16x8 b1 = *reinterpret_cast<const bf16x8*>(Wi_t + bo);
            bf16x8 b2 = *reinterpret_cast<const bf16x8*>(Wi_t + PS + bo);
            bf16x8 b3 = *reinterpret_cast<const bf16x8*>(Wi_t + 2 * PS + bo);
            #pragma unroll
            for (int mt = 0; mt < 2; ++mt) {
                f32x4 A = acc[mt][nt];
                A = __builtin_amdgcn_mfma_f32_16x16x32_bf16(a1[mt], b1, A, 0, 0, 0);
                A = __builtin_amdgcn_mfma_f32_16x16x32_bf16(a1[mt], b2, A, 0, 0, 0);
                A = __builtin_amdgcn_mfma_f32_16x16x32_bf16(a2[mt], b1, A, 0, 0, 0);
                A = __builtin_amdgcn_mfma_f32_16x16x32_bf16(a2[mt], b2, A, 0, 0, 0);
                A = __builtin_amdgcn_mfma_f32_16x16x32_bf16(a1[mt], b3, A, 0, 0, 0);
                A = __builtin_amdgcn_mfma_f32_16x16x32_bf16(a3[mt], b1, A, 0, 0, 0);
                acc[mt][nt] = A;
            }
        }
    }

    const int c = lane & 15;
    const int r0 = (lane >> 4) * 4;
    #pragma unroll
    for (int nt = 0; nt < 2; ++nt) {
        const int n = n_base + nt * 16 + c;
        const float bi = bias[n];
        #pragma unroll
        for (int mt = 0; mt < 2; ++mt) {
            #pragma unroll
            for (int r = 0; r < 4; ++r) {
                const int m = m_base + mt * 16 + r0 + r;
                const int tl = m >> 9, b = m & 511;
                Z0[(size_t)tl * (NB * NH) + tiled_off(b, n, 32)] = acc[mt][nt][r] + bi;
            }
        }
    }
}

// ---------------- grid barrier: flag stores + leader scan -------------------
__device__ __forceinline__ void gridbar(int* flags, int* gen, int target) {
    __syncthreads();
    if (threadIdx.x == 0) {
        __builtin_amdgcn_fence(__ATOMIC_RELEASE, "agent");
        __hip_atomic_store(&flags[blockIdx.x], target, __ATOMIC_RELAXED, __HIP_MEMORY_SCOPE_AGENT);
    }
    if (blockIdx.x == 0) {
        if (threadIdx.x < 64) {
            const int l = threadIdx.x;
            for (;;) {
                int v0 = __hip_atomic_load(&flags[l],       __ATOMIC_RELAXED, __HIP_MEMORY_SCOPE_AGENT);
                int v1 = __hip_atomic_load(&flags[l + 64],  __ATOMIC_RELAXED, __HIP_MEMORY_SCOPE_AGENT);
                int v2 = __hip_atomic_load(&flags[l + 128], __ATOMIC_RELAXED, __HIP_MEMORY_SCOPE_AGENT);
                int v3 = __hip_atomic_load(&flags[l + 192], __ATOMIC_RELAXED, __HIP_MEMORY_SCOPE_AGENT);
                int mn = min(min(v0, v1), min(v2, v3));
                if (__all(mn >= target)) break;
                __builtin_amdgcn_s_sleep(1);
            }
        }
        __syncthreads();
        if (threadIdx.x == 0) {
            __builtin_amdgcn_fence(__ATOMIC_ACQ_REL, "agent");
            __hip_atomic_store(gen, target, __ATOMIC_RELAXED, __HIP_MEMORY_SCOPE_AGENT);
        }
    } else if (threadIdx.x == 0) {
        while (__hip_atomic_load(gen, __ATOMIC_RELAXED, __HIP_MEMORY_SCOPE_AGENT) < target)
            __builtin_amdgcn_s_sleep(2);
    }
    __syncthreads();
    __builtin_amdgcn_fence(__ATOMIC_ACQUIRE, "agent");
}

// ---------------- the pipelined persistent kernel ---------------------------
__global__ __launch_bounds__(256, 1)
void snn_pipe(const float* __restrict__ Z0,
              const __bf16* __restrict__ Wt,
              const __bf16* __restrict__ Wo_t,
              const float* __restrict__ b_h,
              const float* __restrict__ b_out,
              const float* __restrict__ beta_h,
              const float* __restrict__ thr_h,
              const float* __restrict__ beta_o,
              const float* __restrict__ thr_o,
              float* __restrict__ mem0t,
              float* __restrict__ mem123,
              float* __restrict__ mem_o,
              __bf16* __restrict__ spk0, __bf16* __restrict__ spk1,
              __bf16* __restrict__ spk2, __bf16* __restrict__ spk3,
              float* __restrict__ out,
              int* __restrict__ flags, int* __restrict__ gen,
              int t0, int tc)
{
    __shared__ __bf16 Wlds[2 * 32 * 512];   // 64 KB: planes 1,2 of 16-col slice

    const int blk = blockIdx.x;
    const int tid = threadIdx.x;
    const int lane = tid & 63;
    const int w = tid >> 6;

    const int ell = blk >> 6;        // hidden layer 0..2 (if blk<192)
    const int ns  = blk & 63;        // 16-col slice id

    // ---- stage weight planes 1,2 into LDS (hidden blocks only) ----
    if (blk < 192) {
        const __bf16* Wsrc = Wt + (size_t)ell * 3 * (NH * NH) + (size_t)ns * 16384;
        #pragma unroll
        for (int p = 0; p < 2; ++p) {
            const bf16x8* src = reinterpret_cast<const bf16x8*>(Wsrc + (size_t)p * (NH * NH));
            bf16x8* dst = reinterpret_cast<bf16x8*>(Wlds + p * 16384);
            for (int i = tid; i < 2048; i += 256) dst[i] = src[i];
        }
    }
    __syncthreads();

    const size_t SPKS = (size_t)NB * NH;   // elems per spike slot

    for (int p = 0; p <= tc + 3; ++p) {
        if (p > 0 && blk < 192) {
            // ---------- hidden layer ell, timestep s = p-1-ell ----------
            const int s = p - 1 - ell;
            if (s >= 0 && s < tc) {
                const __bf16* Xt = (ell == 0 ? spk0 : (ell == 1 ? spk1 : spk2)) + (size_t)(s & 1) * SPKS;
                __bf16* Yt = (ell == 0 ? spk1 : (ell == 1 ? spk2 : spk3)) + (size_t)(s & 1) * SPKS;
                float* mem = mem123 + (size_t)ell * (NB * NH);
                const float* bias = b_h + ell * NH;
                const float* beta = beta_h + (ell + 1) * NH;
                const float* thr  = thr_h + (ell + 1) * NH;
                const __bf16* W3 = Wt + ((size_t)ell * 3 + 2) * (NH * NH) + (size_t)ns * 16384;
                const int n0 = ns * 16;

                f32x4 acc[8] = {};
                for (int kt = 0; kt < 32; ++kt) {
                    bf16x8 b1 = *reinterpret_cast<const bf16x8*>(Wlds + kt * 512 + lane * 8);
                    bf16x8 b2 = *reinterpret_cast<const bf16x8*>(Wlds + 16384 + kt * 512 + lane * 8);
                    bf16x8 b3 = *reinterpret_cast<const bf16x8*>(W3 + (size_t)kt * 512 + lane * 8);
                    bf16x8 a[8];
                    #pragma unroll
                    for (int i = 0; i < 8; ++i) {
                        const int mt = w * 8 + i;
                        a[i] = *reinterpret_cast<const bf16x8*>(Xt + ((size_t)(mt * 32 + kt) * 64 + lane) * 8);
                    }
                    #pragma unroll
                    for (int i = 0; i < 8; ++i) {
                        acc[i] = __builtin_amdgcn_mfma_f32_16x16x32_bf16(a[i], b1, acc[i], 0, 0, 0);
                        acc[i] = __builtin_amdgcn_mfma_f32_16x16x32_bf16(a[i], b2, acc[i], 0, 0, 0);
                        acc[i] = __builtin_amdgcn_mfma_f32_16x16x32_bf16(a[i], b3, acc[i], 0, 0, 0);
                    }
                }
                const int r0 = (lane >> 4) * 4;
                const int c = lane & 15;
                const int n = n0 + c;
                const float bi = bias[n], be = beta[n], th = thr[n];
                #pragma unroll
                for (int i = 0; i < 8; ++i) {
                    const int bb = (w * 8 + i) * 16 + r0;
                    #pragma unroll
                    for (int r = 0; r < 4; ++r) {
                        const int b = bb + r;
                        float mp = mem[(size_t)b * NH + n];
                        float mn, sp;
                        leaky_upd(acc[i][r] + bi, mp, be, th, mn, sp);
                        mem[(size_t)b * NH + n] = mn;
                        Yt[tiled_off(b, n, 32)] = (__bf16)sp;
                    }
                }
            }
        } else if (p > 0 && blk < 224) {
            // ---------- output layer, timestep s = p-4 ----------
            const int s = p - 4;
            if (s >= 0 && s < tc && w < 3) {
                const __bf16* Xt = spk3 + (size_t)(s & 1) * SPKS;
                const int mt = blk - 192;
                const int nt = w;
                const size_t PS = (size_t)48 * NH;
                f32x4 acc = {};
                for (int kt = 0; kt < 32; ++kt) {
                    bf16x8 a = *reinterpret_cast<const bf16x8*>(Xt + ((size_t)(mt * 32 + kt) * 64 + lane) * 8);
                    const size_t bo = ((size_t)(nt * 32 + kt) * 64 + lane) * 8;
                    bf16x8 b1 = *reinterpret_cast<const bf16x8*>(Wo_t + bo);
                    bf16x8 b2 = *reinterpret_cast<const bf16x8*>(Wo_t + PS + bo);
                    bf16x8 b3 = *reinterpret_cast<const bf16x8*>(Wo_t + 2 * PS + bo);
                    acc = __builtin_amdgcn_mfma_f32_16x16x32_bf16(a, b1, acc, 0, 0, 0);
                    acc = __builtin_amdgcn_mfma_f32_16x16x32_bf16(a, b2, acc, 0, 0, 0);
                    acc = __builtin_amdgcn_mfma_f32_16x16x32_bf16(a, b3, acc, 0, 0, 0);
                }
                const int c = lane & 15, r0 = (lane >> 4) * 4;
                const int o = nt * 16 + c;
                if (o < NO) {
                    const float bi = b_out[o], be = beta_o[o], th = thr_o[o];
                    #pragma unroll
                    for (int r = 0; r < 4; ++r) {
                        const int b = mt * 16 + r0 + r;
                        float mp = mem_o[b * NO + o];
                        float mn, sp;
                        leaky_upd(acc[r] + bi, mp, be, th, mn, sp);
                        mem_o[b * NO + o] = mn;
                        out[((size_t)(t0 + s) * NB + b) * NO + o] = sp;
                    }
                }
            }
        } else if (blk >= 224) {
            // ---------- layer-0 leaky, timestep s = p ----------
            const int s = p;
            if (s < tc) {
                const int cb = blk - 224;
                const float* Zs = Z0 + (size_t)s * (NB * NH);
                __bf16* sp0 = spk0 + (size_t)(s & 1) * SPKS;
                for (int it = 0; it < 8; ++it) {
                    const int i0 = cb * 16384 + it * 2048 + tid * 8;
                    const float* zp = Zs + i0;
                    float* mp = mem0t + i0;
                    const int n8 = ((((i0 >> 9)) & 31) << 5) + (((i0 >> 7) & 3) << 3);

                    float4 za = *reinterpret_cast<const float4*>(zp);
                    float4 zb = *reinterpret_cast<const float4*>(zp + 4);
                    float4 ma = *reinterpret_cast<const float4*>(mp);
                    float4 mb = *reinterpret_cast<const float4*>(mp + 4);
                    float4 e0 = *reinterpret_cast<const float4*>(&beta_h[n8]);
                    float4 e1 = *reinterpret_cast<const float4*>(&beta_h[n8 + 4]);
                    float4 h0 = *reinterpret_cast<const float4*>(&thr_h[n8]);
                    float4 h1 = *reinterpret_cast<const float4*>(&thr_h[n8 + 4]);

                    bf16x8 sv;
                    float mn, sp;
                    leaky_upd(za.x, ma.x, e0.x, h0.x, mn, sp); ma.x = mn; sv[0] = (__bf16)sp;
                    leaky_upd(za.y, ma.y, e0.y, h0.y, mn, sp); ma.y = mn; sv[1] = (__bf16)sp;
                    leaky_upd(za.z, ma.z, e0.z, h0.z, mn, sp); ma.z = mn; sv[2] = (__bf16)sp;
                    leaky_upd(za.w, ma.w, e0.w, h0.w, mn, sp); ma.w = mn; sv[3] = (__bf16)sp;
                    leaky_upd(zb.x, mb.x, e1.x, h1.x, mn, sp); mb.x = mn; sv[4] = (__bf16)sp;
                    leaky_upd(zb.y, mb.y, e1.y, h1.y, mn, sp); mb.y = mn; sv[5] = (__bf16)sp;
                    leaky_upd(zb.z, mb.z, e1.z, h1.z, mn, sp); mb.z = mn; sv[6] = (__bf16)sp;
                    leaky_upd(zb.w, mb.w, e1.w, h1.w, mn, sp); mb.w = mn; sv[7] = (__bf16)sp;

                    *reinterpret_cast<float4*>(mp)     = ma;
                    *reinterpret_cast<float4*>(mp + 4) = mb;
                    *reinterpret_cast<bf16x8*>(sp0 + i0) = sv;
                }
            }
        }
        gridbar(flags, gen, p + 1);
    }
}

// ---------------- launch ----------------------------------------------------
extern "C" void kernel_launch(void* const* d_in, const int* in_sizes, int n_in,
                              void* d_out, int out_size, void* d_ws, size_t ws_size,
                              hipStream_t stream) {
    const float* data   = (const float*)d_in[0];
    const float* W_in   = (const float*)d_in[1];
    const float* b_in   = (const float*)d_in[2];
    const float* W_h    = (const float*)d_in[3];
    const float* b_h    = (const float*)d_in[4];
    const float* W_out  = (const float*)d_in[5];
    const float* b_out  = (const float*)d_in[6];
    const float* beta_h = (const float*)d_in[7];
    const float* thr_h  = (const float*)d_in[8];
    const float* beta_o = (const float*)d_in[9];
    const float* thr_o  = (const float*)d_in[10];
    float* out = (float*)d_out;

    char* ws = (char*)d_ws;
    float*  mem0t = (float*)(ws + WS_MEM0);
    float*  mem123= (float*)(ws + WS_MEM123);
    float*  mem_o = (float*)(ws + WS_MEMO);
    int*    flags = (int*)(ws + WS_FLAGS);
    int*    gen   = (int*)(ws + WS_GEN);
    __bf16* spk0  = (__bf16*)(ws + WS_SPK0);
    __bf16* spk1  = (__bf16*)(ws + WS_SPK1);
    __bf16* spk2  = (__bf16*)(ws + WS_SPK2);
    __bf16* spk3  = (__bf16*)(ws + WS_SPK3);
    __bf16* Wt    = (__bf16*)(ws + WS_WT);
    __bf16* Wi_t  = (__bf16*)(ws + WS_WIT);
    __bf16* Wo_t  = (__bf16*)(ws + WS_WOT);
    float*  Z0    = (float*)(ws + WS_Z0);

    const size_t STEPB = (size_t)NB * NH * sizeof(float);   // 2 MB
    size_t avail = (ws_size > WS_Z0) ? (ws_size - WS_Z0) / STEPB : 1;
    int Tc = (int)(avail < 1 ? 1 : (avail > TT ? TT : avail));

    hipMemsetAsync(ws, 0, WS_FLAGS, stream);   // mem0t + mem123 + mem_o
    split_weights<<<dim3(1536), dim3(256), 0, stream>>>(W_h, Wt);
    split_win<<<dim3(256), dim3(256), 0, stream>>>(W_in, Wi_t);
    split_wout<<<dim3(24), dim3(256), 0, stream>>>(W_out, Wo_t);

    for (int t0c = 0; t0c < TT; t0c += Tc) {
        const int tcc = (TT - t0c < Tc) ? (TT - t0c) : Tc;
        z0_gemm<<<dim3(NH / 64, tcc * (NB / 64)), dim3(256), 0, stream>>>(
            data + (size_t)t0c * NB * NI, Wi_t, b_in, Z0);
        hipMemsetAsync(ws + WS_FLAGS, 0, 1280, stream);   // flags + gen
        snn_pipe<<<dim3(NBLK), dim3(256), 0, stream>>>(
            Z0, Wt, Wo_t, b_h, b_out, beta_h, thr_h, beta_o, thr_o,
            mem0t, mem123, mem_o, spk0, spk1, spk2, spk3, out,
            flags, gen, t0c, tcc);
    }
}

// Round 6
// 3856.926 us; speedup vs baseline: 5.0815x; 1.6210x over previous
//
#include <hip/hip_runtime.h>
#include <hip/hip_bf16.h>

// SNN, 5 layers, T=100, B=512.  R6:
//  - spk0_all precomputed per chunk (layer-0 recurrence is self-contained).
//  - snn_pipe: 192 persistent blocks x 512 threads (2 waves/SIMD), 3-layer
//    skewed pipeline, ALL 3 weight planes in LDS (96KB), membranes in
//    REGISTERS (global only at chunk boundaries). tc+2 grid barriers.
//  - output layer post-computed: batched zout_gemm + tiny sequential out_seq.

#define NB 512
#define NH 1024
#define NI 512
#define NO 35
#define TT 100
#define NBLK_P 192

typedef __bf16 bf16x8 __attribute__((ext_vector_type(8)));
typedef __bf16 bf16x4 __attribute__((ext_vector_type(4)));
typedef float f32x4 __attribute__((ext_vector_type(4)));

// MFMA 16x16x32 operand tiling over [rows][K]: [row/16][k/32][lane][8],
// lane = (row&15) | (((k>>3)&3)<<4), elem j = k&7.  KT = K/32.
__device__ __forceinline__ size_t tiled_off(int row, int k, int KT) {
    return ((size_t)((row >> 4) * KT + (k >> 5)) * 64
            + (row & 15) + (((k >> 3) & 3) << 4)) * 8 + (k & 7);
}

__device__ __forceinline__ void leaky_upd(float zin, float mprev, float be, float th,
                                          float& mnew, float& spk) {
    float rs = (mprev - th > 0.0f) ? th : 0.0f;          // reset*thr (detached)
    float bc = fminf(fmaxf(be, 0.0f), 1.0f);             // clip(beta,0,1)
    mnew = bc * mprev + zin - rs;
    spk  = (mnew - th > 0.0f) ? 1.0f : 0.0f;
}

// ---------------- ws layout (bytes) ----------------
#define WS_MEM123   0u           // 6,291,456 (mem L1..L3 row-major, chunk-persist)
#define WS_MEM0     6291456u     // 2,097,152 (layer-0 mem, tiled-linear fp32)
#define WS_MEMO     8388608u     // 71,680    (output mem, flat 512*35)
#define WS_FLAGS    8460288u     // 1,024
#define WS_GEN      8461312u     // 256
#define WS_SPK1     8461568u     // 2 x 1MB ring
#define WS_SPK2     10558720u    // 2 x 1MB ring
#define WS_WT       12655872u    // 18,874,368 (W_h: 3 layers x 3 planes, tiled)
#define WS_WIT      31530240u    // 3,145,728  (W_in: 3 planes, tiled KT=16)
#define WS_WOT      34675968u    // 294,912    (W_out padded 48 rows, 3 planes)
#define WS_DYN      34970880u    // per-step arrays
// per step: zout 98,304 | spk0 1,048,576 | union(Z0 fp32 / spk3 bf16) 2,097,152
#define STEP_BYTES  3244032u

// ---------------- weight splits ----------------
__global__ __launch_bounds__(256)
void split_weights(const float* __restrict__ W_h, __bf16* __restrict__ Wt) {
    const int id = blockIdx.x * 256 + threadIdx.x;   // 3 * 1024 * 128
    const int layer = id >> 17;
    const int rem = id & 131071;
    const int n = rem >> 7;
    const int k0 = (rem & 127) << 3;
    const float* src = W_h + ((size_t)layer * NH + n) * NH + k0;
    __bf16* dst = Wt + (size_t)layer * 3 * NH * NH;
    const size_t PS = (size_t)NH * NH;
    const size_t off = tiled_off(n, k0, 32);
    bf16x8 p1, p2, p3;
    #pragma unroll
    for (int j = 0; j < 8; ++j) {
        float w = src[j];
        __bf16 a = (__bf16)w;  float r1 = w - (float)a;
        __bf16 b = (__bf16)r1; float r2 = r1 - (float)b;
        __bf16 c = (__bf16)r2;
        p1[j] = a; p2[j] = b; p3[j] = c;
    }
    *reinterpret_cast<bf16x8*>(dst + 0 * PS + off) = p1;
    *reinterpret_cast<bf16x8*>(dst + 1 * PS + off) = p2;
    *reinterpret_cast<bf16x8*>(dst + 2 * PS + off) = p3;
}

__global__ __launch_bounds__(256)
void split_win(const float* __restrict__ W_in, __bf16* __restrict__ Wi_t) {
    const int id = blockIdx.x * 256 + threadIdx.x;   // 1024 * 64
    const int n = id >> 6;
    const int k0 = (id & 63) << 3;
    const float* src = W_in + (size_t)n * NI + k0;
    const size_t PS = (size_t)NH * NI;
    const size_t off = tiled_off(n, k0, 16);
    bf16x8 p1, p2, p3;
    #pragma unroll
    for (int j = 0; j < 8; ++j) {
        float w = src[j];
        __bf16 a = (__bf16)w;  float r1 = w - (float)a;
        __bf16 b = (__bf16)r1; float r2 = r1 - (float)b;
        __bf16 c = (__bf16)r2;
        p1[j] = a; p2[j] = b; p3[j] = c;
    }
    *reinterpret_cast<bf16x8*>(Wi_t + 0 * PS + off) = p1;
    *reinterpret_cast<bf16x8*>(Wi_t + 1 * PS + off) = p2;
    *reinterpret_cast<bf16x8*>(Wi_t + 2 * PS + off) = p3;
}

__global__ __launch_bounds__(256)
void split_wout(const float* __restrict__ W_out, __bf16* __restrict__ Wo_t) {
    const int id = blockIdx.x * 256 + threadIdx.x;   // 48 * 128
    if (id >= 48 * 128) return;
    const int o = id >> 7;
    const int k0 = (id & 127) << 3;
    const size_t PS = (size_t)48 * NH;
    const size_t off = tiled_off(o, k0, 32);
    bf16x8 p1 = {}, p2 = {}, p3 = {};
    if (o < NO) {
        const float* src = W_out + (size_t)o * NH + k0;
        #pragma unroll
        for (int j = 0; j < 8; ++j) {
            float w = src[j];
            __bf16 a = (__bf16)w;  float r1 = w - (float)a;
            __bf16 b = (__bf16)r1; float r2 = r1 - (float)b;
            __bf16 c = (__bf16)r2;
            p1[j] = a; p2[j] = b; p3[j] = c;
        }
    }
    *reinterpret_cast<bf16x8*>(Wo_t + 0 * PS + off) = p1;
    *reinterpret_cast<bf16x8*>(Wo_t + 1 * PS + off) = p2;
    *reinterpret_cast<bf16x8*>(Wo_t + 2 * PS + off) = p3;
}

// ---------------- Z0 = data @ W_in^T + b_in (6-term bf16 MFMA) --------------
__global__ __launch_bounds__(256)
void z0_gemm(const float* __restrict__ X,      // [tc*NB][NI]
             const __bf16* __restrict__ Wi_t,  // 3 planes tiled KT=16
             const float* __restrict__ bias,
             float* __restrict__ Z0)           // [tc][NB*NH tiled] fp32
{
    const int tid = threadIdx.x;
    const int lane = tid & 63;
    const int w = tid >> 6;
    const int wm = w >> 1, wn = w & 1;
    const int m_base = blockIdx.y * 64 + wm * 32;
    const int n_base = blockIdx.x * 64 + wn * 32;
    const size_t PS = (size_t)NH * NI;

    f32x4 acc[2][2] = {};
    bf16x8 a1[2], a2[2], a3[2];

    for (int kt = 0; kt < 16; ++kt) {
        #pragma unroll
        for (int mt = 0; mt < 2; ++mt) {
            const int row = m_base + mt * 16 + (lane & 15);
            const float* src = X + (size_t)row * NI + kt * 32 + ((lane >> 4) << 3);
            float4 v0 = *reinterpret_cast<const float4*>(src);
            float4 v1 = *reinterpret_cast<const float4*>(src + 4);
            float xv[8] = {v0.x, v0.y, v0.z, v0.w, v1.x, v1.y, v1.z, v1.w};
            #pragma unroll
            for (int j = 0; j < 8; ++j) {
                float x = xv[j];
                __bf16 h1 = (__bf16)x;  float r1 = x - (float)h1;
                __bf16 h2 = (__bf16)r1; float r2 = r1 - (float)h2;
                __bf16 h3 = (__bf16)r2;
                a1[mt][j] = h1; a2[mt][j] = h2; a3[mt][j] = h3;
            }
        }
        #pragma unroll
        for (int nt = 0; nt < 2; ++nt) {
            const size_t bo = ((size_t)(((n_base >> 4) + nt) * 16 + kt) * 64 + lane) * 8;
            bf16x8 b1 = *reinterpret_cast<const bf16x8*>(Wi_t + bo);
            bf16x8 b2 = *reinterpret_cast<const bf16x8*>(Wi_t + PS + bo);
            bf16x8 b3 = *reinterpret_cast<const bf16x8*>(Wi_t + 2 * PS + bo);
            #pragma unroll
            for (int mt = 0; mt < 2; ++mt) {
                f32x4 A = acc[mt][nt];
                A = __builtin_amdgcn_mfma_f32_16x16x32_bf16(a1[mt], b1, A, 0, 0, 0);
                A = __builtin_amdgcn_mfma_f32_16x16x32_bf16(a1[mt], b2, A, 0, 0, 0);
                A = __builtin_amdgcn_mfma_f32_16x16x32_bf16(a2[mt], b1, A, 0, 0, 0);
                A = __builtin_amdgcn_mfma_f32_16x16x32_bf16(a2[mt], b2, A, 0, 0, 0);
                A = __builtin_amdgcn_mfma_f32_16x16x32_bf16(a1[mt], b3, A, 0, 0, 0);
                A = __builtin_amdgcn_mfma_f32_16x16x32_bf16(a3[mt], b1, A, 0, 0, 0);
                acc[mt][nt] = A;
            }
        }
    }

    const int c = lane & 15;
    const int r0 = (lane >> 4) * 4;
    #pragma unroll
    for (int nt = 0; nt < 2; ++nt) {
        const int n = n_base + nt * 16 + c;
        const float bi = bias[n];
        #pragma unroll
        for (int mt = 0; mt < 2; ++mt) {
            #pragma unroll
            for (int r = 0; r < 4; ++r) {
                const int m = m_base + mt * 16 + r0 + r;
                const int tl = m >> 9, b = m & 511;
                Z0[(size_t)tl * (NB * NH) + tiled_off(b, n, 32)] = acc[mt][nt][r] + bi;
            }
        }
    }
}

// ---------------- layer-0 sequential leaky over the whole chunk -------------
__global__ __launch_bounds__(256)
void leaky0_seq(const float* __restrict__ Z0,      // [tc][NB*NH tiled]
                __bf16* __restrict__ spk0_all,     // [tc][NB*NH tiled]
                float* __restrict__ mem0_g,        // [NB*NH tiled]
                const float* __restrict__ beta0,
                const float* __restrict__ thr0,
                int tc)
{
    const int g = blockIdx.x * 256 + threadIdx.x;    // 131072 threads
    const int i0 = g * 4;
    const int n0 = (((i0 >> 9) & 31) << 5) + (((i0 >> 7) & 3) << 3) + (i0 & 7);

    float4 mem = *reinterpret_cast<const float4*>(mem0_g + i0);
    float4 be  = *reinterpret_cast<const float4*>(beta0 + n0);
    float4 th  = *reinterpret_cast<const float4*>(thr0 + n0);

    for (int s = 0; s < tc; ++s) {
        float4 z = *reinterpret_cast<const float4*>(Z0 + (size_t)s * (NB * NH) + i0);
        bf16x4 sv;
        float mn, sp;
        leaky_upd(z.x, mem.x, be.x, th.x, mn, sp); mem.x = mn; sv[0] = (__bf16)sp;
        leaky_upd(z.y, mem.y, be.y, th.y, mn, sp); mem.y = mn; sv[1] = (__bf16)sp;
        leaky_upd(z.z, mem.z, be.z, th.z, mn, sp); mem.z = mn; sv[2] = (__bf16)sp;
        leaky_upd(z.w, mem.w, be.w, th.w, mn, sp); mem.w = mn; sv[3] = (__bf16)sp;
        *reinterpret_cast<bf16x4*>(spk0_all + (size_t)s * (NB * NH) + i0) = sv;
    }
    *reinterpret_cast<float4*>(mem0_g + i0) = mem;
}

// ---------------- grid barrier: flag stores + leader scan -------------------
__device__ __forceinline__ void gridbar(int* flags, int* gen, int target) {
    __syncthreads();
    if (threadIdx.x == 0) {
        __builtin_amdgcn_fence(__ATOMIC_RELEASE, "agent");
        __hip_atomic_store(&flags[blockIdx.x], target, __ATOMIC_RELAXED, __HIP_MEMORY_SCOPE_AGENT);
    }
    if (blockIdx.x == 0) {
        if (threadIdx.x < 64) {
            const int l = threadIdx.x;
            for (;;) {
                int v0 = __hip_atomic_load(&flags[l],       __ATOMIC_RELAXED, __HIP_MEMORY_SCOPE_AGENT);
                int v1 = __hip_atomic_load(&flags[l + 64],  __ATOMIC_RELAXED, __HIP_MEMORY_SCOPE_AGENT);
                int v2 = __hip_atomic_load(&flags[l + 128], __ATOMIC_RELAXED, __HIP_MEMORY_SCOPE_AGENT);
                int mn = min(min(v0, v1), v2);
                if (__all(mn >= target)) break;
                __builtin_amdgcn_s_sleep(1);
            }
        }
        __syncthreads();
        if (threadIdx.x == 0) {
            __builtin_amdgcn_fence(__ATOMIC_ACQ_REL, "agent");
            __hip_atomic_store(gen, target, __ATOMIC_RELAXED, __HIP_MEMORY_SCOPE_AGENT);
        }
    } else if (threadIdx.x == 0) {
        while (__hip_atomic_load(gen, __ATOMIC_RELAXED, __HIP_MEMORY_SCOPE_AGENT) < target)
            __builtin_amdgcn_s_sleep(2);
    }
    __syncthreads();
    __builtin_amdgcn_fence(__ATOMIC_ACQUIRE, "agent");
}

// ---------------- hidden-layer pipeline (persistent) ------------------------
__global__ __launch_bounds__(512, 1)
void snn_pipe(const __bf16* __restrict__ spk0_all,  // [tc][tiled]
              __bf16* __restrict__ spk3_all,        // [tc][tiled]
              const __bf16* __restrict__ Wt,
              const float* __restrict__ b_h,
              const float* __restrict__ beta_h,
              const float* __restrict__ thr_h,
              float* __restrict__ mem123,           // chunk-persist
              __bf16* __restrict__ spk1,            // 2-slot ring
              __bf16* __restrict__ spk2,            // 2-slot ring
              int* __restrict__ flags, int* __restrict__ gen,
              int tc)
{
    __shared__ __bf16 Wlds[3 * 32 * 512];   // 96 KB: all 3 planes, 16-col slice

    const int blk  = blockIdx.x;
    const int tid  = threadIdx.x;
    const int lane = tid & 63;
    const int w    = tid >> 6;              // 8 waves
    const int ell  = blk >> 6;              // layer 0..2
    const int ns   = blk & 63;              // 16-col slice

    // stage all 3 weight planes into LDS
    {
        const __bf16* Wsrc = Wt + (size_t)ell * 3 * (NH * NH) + (size_t)ns * 16384;
        #pragma unroll
        for (int p = 0; p < 3; ++p) {
            const bf16x8* src = reinterpret_cast<const bf16x8*>(Wsrc + (size_t)p * (NH * NH));
            bf16x8* dst = reinterpret_cast<bf16x8*>(Wlds + p * 16384);
            for (int i = tid; i < 2048; i += 512) dst[i] = src[i];
        }
    }

    // per-thread fixed output elements: col n, rows (w*4+i)*16 + r0 + r
    const int c  = lane & 15;
    const int r0 = (lane >> 4) * 4;
    const int n  = ns * 16 + c;
    float* memg = mem123 + (size_t)ell * (NB * NH);
    const float bi = b_h[ell * NH + n];
    const float be = beta_h[(ell + 1) * NH + n];
    const float th = thr_h[(ell + 1) * NH + n];

    float memr[16];
    #pragma unroll
    for (int i = 0; i < 4; ++i)
        #pragma unroll
        for (int r = 0; r < 4; ++r)
            memr[i * 4 + r] = memg[(size_t)((w * 4 + i) * 16 + r0 + r) * NH + n];

    // spike-store column offset within a row-tile (elems)
    const int st_col = ((n >> 5) << 9) + (((n >> 3) & 3) << 7) + (n & 7);
    const size_t SPKS = (size_t)NB * NH;

    __syncthreads();

    for (int p = 0; p < tc + 2; ++p) {
        const int s = p - ell;
        if (s >= 0 && s < tc) {
            const __bf16* Xt = (ell == 0) ? spk0_all + (size_t)s * SPKS
                              : (ell == 1) ? spk1 + (size_t)(s & 1) * SPKS
                                           : spk2 + (size_t)(s & 1) * SPKS;
            __bf16* Yt = (ell == 0) ? spk1 + (size_t)(s & 1) * SPKS
                        : (ell == 1) ? spk2 + (size_t)(s & 1) * SPKS
                                     : spk3_all + (size_t)s * SPKS;

            f32x4 acc[4] = {};
            for (int kt = 0; kt < 32; ++kt) {
                const int lo = kt * 512 + lane * 8;
                bf16x8 b1 = *reinterpret_cast<const bf16x8*>(Wlds + lo);
                bf16x8 b2 = *reinterpret_cast<const bf16x8*>(Wlds + 16384 + lo);
                bf16x8 b3 = *reinterpret_cast<const bf16x8*>(Wlds + 32768 + lo);
                bf16x8 a[4];
                #pragma unroll
                for (int i = 0; i < 4; ++i)
                    a[i] = *reinterpret_cast<const bf16x8*>(Xt + (size_t)(w * 4 + i) * 16384 + lo);
                #pragma unroll
                for (int i = 0; i < 4; ++i) {
                    acc[i] = __builtin_amdgcn_mfma_f32_16x16x32_bf16(a[i], b1, acc[i], 0, 0, 0);
                    acc[i] = __builtin_amdgcn_mfma_f32_16x16x32_bf16(a[i], b2, acc[i], 0, 0, 0);
                    acc[i] = __builtin_amdgcn_mfma_f32_16x16x32_bf16(a[i], b3, acc[i], 0, 0, 0);
                }
            }
            #pragma unroll
            for (int i = 0; i < 4; ++i) {
                #pragma unroll
                for (int r = 0; r < 4; ++r) {
                    float mn, sp;
                    leaky_upd(acc[i][r] + bi, memr[i * 4 + r], be, th, mn, sp);
                    memr[i * 4 + r] = mn;
                    Yt[(size_t)(w * 4 + i) * 16384 + st_col + (size_t)(r0 + r) * 8] = (__bf16)sp;
                }
            }
        }
        gridbar(flags, gen, p + 1);
    }

    #pragma unroll
    for (int i = 0; i < 4; ++i)
        #pragma unroll
        for (int r = 0; r < 4; ++r)
            memg[(size_t)((w * 4 + i) * 16 + r0 + r) * NH + n] = memr[i * 4 + r];
}

// ---------------- batched output GEMM over the chunk ------------------------
__global__ __launch_bounds__(256)
void zout_gemm(const __bf16* __restrict__ spk3_all,  // [tc][tiled]
               const __bf16* __restrict__ Wo_t,      // 3 planes, 48 rows
               const float* __restrict__ b_out,
               float* __restrict__ zout)             // [tc][512][48]
{
    const int s  = blockIdx.x >> 2;
    const int rg = blockIdx.x & 3;
    const int tid = threadIdx.x;
    const int lane = tid & 63;
    const int w = tid >> 6;                 // 4 waves, 2 row-tiles each
    const size_t PS = (size_t)48 * NH;
    const size_t SPKS = (size_t)NB * NH;

    f32x4 acc[2][3] = {};
    for (int kt = 0; kt < 32; ++kt) {
        const int lo = kt * 512 + lane * 8;
        bf16x8 a[2];
        #pragma unroll
        for (int i = 0; i < 2; ++i) {
            const int gmt = rg * 8 + w * 2 + i;
            a[i] = *reinterpret_cast<const bf16x8*>(spk3_all + s * SPKS + (size_t)gmt * 16384 + lo);
        }
        #pragma unroll
        for (int nt = 0; nt < 3; ++nt) {
            const size_t bo = (size_t)nt * 16384 + lo;
            bf16x8 b1 = *reinterpret_cast<const bf16x8*>(Wo_t + bo);
            bf16x8 b2 = *reinterpret_cast<const bf16x8*>(Wo_t + PS + bo);
            bf16x8 b3 = *reinterpret_cast<const bf16x8*>(Wo_t + 2 * PS + bo);
            #pragma unroll
            for (int i = 0; i < 2; ++i) {
                acc[i][nt] = __builtin_amdgcn_mfma_f32_16x16x32_bf16(a[i], b1, acc[i][nt], 0, 0, 0);
                acc[i][nt] = __builtin_amdgcn_mfma_f32_16x16x32_bf16(a[i], b2, acc[i][nt], 0, 0, 0);
                acc[i][nt] = __builtin_amdgcn_mfma_f32_16x16x32_bf16(a[i], b3, acc[i][nt], 0, 0, 0);
            }
        }
    }

    const int c = lane & 15, r0 = (lane >> 4) * 4;
    #pragma unroll
    for (int nt = 0; nt < 3; ++nt) {
        const int o = nt * 16 + c;
        if (o < NO) {
            const float bi = b_out[o];
            #pragma unroll
            for (int i = 0; i < 2; ++i) {
                #pragma unroll
                for (int r = 0; r < 4; ++r) {
                    const int b = (rg * 8 + w * 2 + i) * 16 + r0 + r;
                    zout[((size_t)s * NB + b) * 48 + o] = acc[i][nt][r] + bi;
                }
            }
        }
    }
}

// ---------------- sequential output leaky ------------------------------------
__global__ __launch_bounds__(256)
void out_seq(const float* __restrict__ zout,   // [tc][512][48]
             float* __restrict__ out,          // [TT][512][35]
             float* __restrict__ memo_g,       // [512*35]
             const float* __restrict__ beta_o,
             const float* __restrict__ thr_o,
             int t0, int tc)
{
    const int g = blockIdx.x * 256 + threadIdx.x;
    if (g >= NB * NO) return;
    const int b = g / NO;
    const int o = g - b * NO;
    float mem = memo_g[g];
    const float be = beta_o[o], th = thr_o[o];
    for (int s = 0; s < tc; ++s) {
        float z = zout[((size_t)s * NB + b) * 48 + o];
        float mn, sp;
        leaky_upd(z, mem, be, th, mn, sp);
        mem = mn;
        out[((size_t)(t0 + s) * NB + b) * NO + o] = sp;
    }
    memo_g[g] = mem;
}

// ---------------- launch ----------------------------------------------------
extern "C" void kernel_launch(void* const* d_in, const int* in_sizes, int n_in,
                              void* d_out, int out_size, void* d_ws, size_t ws_size,
                              hipStream_t stream) {
    const float* data   = (const float*)d_in[0];
    const float* W_in   = (const float*)d_in[1];
    const float* b_in   = (const float*)d_in[2];
    const float* W_h    = (const float*)d_in[3];
    const float* b_h    = (const float*)d_in[4];
    const float* W_out  = (const float*)d_in[5];
    const float* b_out  = (const float*)d_in[6];
    const float* beta_h = (const float*)d_in[7];
    const float* thr_h  = (const float*)d_in[8];
    const float* beta_o = (const float*)d_in[9];
    const float* thr_o  = (const float*)d_in[10];
    float* out = (float*)d_out;

    char* ws = (char*)d_ws;
    float*  mem123 = (float*)(ws + WS_MEM123);
    float*  mem0_g = (float*)(ws + WS_MEM0);
    float*  memo_g = (float*)(ws + WS_MEMO);
    int*    flags  = (int*)(ws + WS_FLAGS);
    int*    gen    = (int*)(ws + WS_GEN);
    __bf16* spk1   = (__bf16*)(ws + WS_SPK1);
    __bf16* spk2   = (__bf16*)(ws + WS_SPK2);
    __bf16* Wt     = (__bf16*)(ws + WS_WT);
    __bf16* Wi_t   = (__bf16*)(ws + WS_WIT);
    __bf16* Wo_t   = (__bf16*)(ws + WS_WOT);

    size_t avail = (ws_size > WS_DYN) ? (ws_size - WS_DYN) / STEP_BYTES : 1;
    int Tc = (int)(avail < 1 ? 1 : (avail > TT ? TT : avail));

    float*  zout     = (float*)(ws + WS_DYN);
    __bf16* spk0_all = (__bf16*)(ws + WS_DYN + (size_t)Tc * 98304u);
    char*   unionb   = ws + WS_DYN + (size_t)Tc * (98304u + 1048576u);
    float*  Z0       = (float*)unionb;            // [Tc][NB*NH] fp32
    __bf16* spk3_all = (__bf16*)unionb;           // [Tc][NB*NH] bf16 (after Z0 dead)

    hipMemsetAsync(ws, 0, WS_FLAGS, stream);      // mem123 + mem0 + memo
    split_weights<<<dim3(1536), dim3(256), 0, stream>>>(W_h, Wt);
    split_win<<<dim3(256), dim3(256), 0, stream>>>(W_in, Wi_t);
    split_wout<<<dim3(24), dim3(256), 0, stream>>>(W_out, Wo_t);

    for (int t0c = 0; t0c < TT; t0c += Tc) {
        const int tcc = (TT - t0c < Tc) ? (TT - t0c) : Tc;
        z0_gemm<<<dim3(NH / 64, tcc * (NB / 64)), dim3(256), 0, stream>>>(
            data + (size_t)t0c * NB * NI, Wi_t, b_in, Z0);
        leaky0_seq<<<dim3(512), dim3(256), 0, stream>>>(
            Z0, spk0_all, mem0_g, beta_h, thr_h, tcc);
        hipMemsetAsync(ws + WS_FLAGS, 0, 1280, stream);   // flags + gen
        snn_pipe<<<dim3(NBLK_P), dim3(512), 0, stream>>>(
            spk0_all, spk3_all, Wt, b_h, beta_h, thr_h,
            mem123, spk1, spk2, flags, gen, tcc);
        zout_gemm<<<dim3(tcc * 4), dim3(256), 0, stream>>>(
            spk3_all, Wo_t, b_out, zout);
        out_seq<<<dim3((NB * NO + 255) / 256), dim3(256), 0, stream>>>(
            zout, out, memo_g, beta_o, thr_o, t0c, tcc);
    }
}

// Round 7
// 2703.855 us; speedup vs baseline: 7.2486x; 1.4265x over previous
//
#include <hip/hip_runtime.h>
#include <hip/hip_bf16.h>

// SNN, 5 layers, T=100, B=512.  R7 = R6 + NT=4 time-batched pipeline phases.
//  - snn_pipe: 192 persistent blocks x 512 threads, 3-layer skewed pipeline,
//    NT=4 steps per phase (27 grid barriers instead of 102), steps processed
//    in PAIRS inside the K-loop (shared LDS B-frags, 24 MFMA/kt, 2 acc chains).
//    All 3 weight planes in LDS (96KB); membranes in registers.
//  - layer 0 / output layer off the serial path (z0_gemm, leaky0_seq,
//    zout_gemm, out_seq), as in R6.

#define NB 512
#define NH 1024
#define NI 512
#define NO 35
#define TT 100
#define NBLK_P 192
#define NT 4

typedef __bf16 bf16x8 __attribute__((ext_vector_type(8)));
typedef __bf16 bf16x4 __attribute__((ext_vector_type(4)));
typedef float f32x4 __attribute__((ext_vector_type(4)));

// MFMA 16x16x32 operand tiling over [rows][K]: [row/16][k/32][lane][8],
// lane = (row&15) | (((k>>3)&3)<<4), elem j = k&7.  KT = K/32.
__device__ __forceinline__ size_t tiled_off(int row, int k, int KT) {
    return ((size_t)((row >> 4) * KT + (k >> 5)) * 64
            + (row & 15) + (((k >> 3) & 3) << 4)) * 8 + (k & 7);
}

__device__ __forceinline__ void leaky_upd(float zin, float mprev, float be, float th,
                                          float& mnew, float& spk) {
    float rs = (mprev - th > 0.0f) ? th : 0.0f;          // reset*thr (detached)
    float bc = fminf(fmaxf(be, 0.0f), 1.0f);             // clip(beta,0,1)
    mnew = bc * mprev + zin - rs;
    spk  = (mnew - th > 0.0f) ? 1.0f : 0.0f;
}

// ---------------- ws layout (bytes) ----------------
#define WS_MEM123   0u           // 6,291,456 (mem L1..L3 row-major, chunk-persist)
#define WS_MEM0     6291456u     // 2,097,152 (layer-0 mem, tiled-linear fp32)
#define WS_MEMO     8388608u     // 71,680    (output mem, flat 512*35)
#define WS_FLAGS    8460288u     // 1,024
#define WS_GEN      8461312u     // 256
#define WS_SPK1     8461568u     // 2*NT MB ring = 8,388,608
#define WS_SPK2     16850176u    // 8,388,608
#define WS_WT       25238784u    // 18,874,368 (W_h: 3 layers x 3 planes, tiled)
#define WS_WIT      44113152u    // 3,145,728  (W_in: 3 planes, tiled KT=16)
#define WS_WOT      47258880u    // 294,912    (W_out padded 48 rows, 3 planes)
#define WS_DYN      47553792u    // per-step arrays
// per step: zout 98,304 | spk0 1,048,576 | union(Z0 fp32 / spk3 bf16) 2,097,152
#define STEP_BYTES  3244032u

// ---------------- weight splits ----------------
__global__ __launch_bounds__(256)
void split_weights(const float* __restrict__ W_h, __bf16* __restrict__ Wt) {
    const int id = blockIdx.x * 256 + threadIdx.x;   // 3 * 1024 * 128
    const int layer = id >> 17;
    const int rem = id & 131071;
    const int n = rem >> 7;
    const int k0 = (rem & 127) << 3;
    const float* src = W_h + ((size_t)layer * NH + n) * NH + k0;
    __bf16* dst = Wt + (size_t)layer * 3 * NH * NH;
    const size_t PS = (size_t)NH * NH;
    const size_t off = tiled_off(n, k0, 32);
    bf16x8 p1, p2, p3;
    #pragma unroll
    for (int j = 0; j < 8; ++j) {
        float w = src[j];
        __bf16 a = (__bf16)w;  float r1 = w - (float)a;
        __bf16 b = (__bf16)r1; float r2 = r1 - (float)b;
        __bf16 c = (__bf16)r2;
        p1[j] = a; p2[j] = b; p3[j] = c;
    }
    *reinterpret_cast<bf16x8*>(dst + 0 * PS + off) = p1;
    *reinterpret_cast<bf16x8*>(dst + 1 * PS + off) = p2;
    *reinterpret_cast<bf16x8*>(dst + 2 * PS + off) = p3;
}

__global__ __launch_bounds__(256)
void split_win(const float* __restrict__ W_in, __bf16* __restrict__ Wi_t) {
    const int id = blockIdx.x * 256 + threadIdx.x;   // 1024 * 64
    const int n = id >> 6;
    const int k0 = (id & 63) << 3;
    const float* src = W_in + (size_t)n * NI + k0;
    const size_t PS = (size_t)NH * NI;
    const size_t off = tiled_off(n, k0, 16);
    bf16x8 p1, p2, p3;
    #pragma unroll
    for (int j = 0; j < 8; ++j) {
        float w = src[j];
        __bf16 a = (__bf16)w;  float r1 = w - (float)a;
        __bf16 b = (__bf16)r1; float r2 = r1 - (float)b;
        __bf16 c = (__bf16)r2;
        p1[j] = a; p2[j] = b; p3[j] = c;
    }
    *reinterpret_cast<bf16x8*>(Wi_t + 0 * PS + off) = p1;
    *reinterpret_cast<bf16x8*>(Wi_t + 1 * PS + off) = p2;
    *reinterpret_cast<bf16x8*>(Wi_t + 2 * PS + off) = p3;
}

__global__ __launch_bounds__(256)
void split_wout(const float* __restrict__ W_out, __bf16* __restrict__ Wo_t) {
    const int id = blockIdx.x * 256 + threadIdx.x;   // 48 * 128
    if (id >= 48 * 128) return;
    const int o = id >> 7;
    const int k0 = (id & 127) << 3;
    const size_t PS = (size_t)48 * NH;
    const size_t off = tiled_off(o, k0, 32);
    bf16x8 p1 = {}, p2 = {}, p3 = {};
    if (o < NO) {
        const float* src = W_out + (size_t)o * NH + k0;
        #pragma unroll
        for (int j = 0; j < 8; ++j) {
            float w = src[j];
            __bf16 a = (__bf16)w;  float r1 = w - (float)a;
            __bf16 b = (__bf16)r1; float r2 = r1 - (float)b;
            __bf16 c = (__bf16)r2;
            p1[j] = a; p2[j] = b; p3[j] = c;
        }
    }
    *reinterpret_cast<bf16x8*>(Wo_t + 0 * PS + off) = p1;
    *reinterpret_cast<bf16x8*>(Wo_t + 1 * PS + off) = p2;
    *reinterpret_cast<bf16x8*>(Wo_t + 2 * PS + off) = p3;
}

// ---------------- Z0 = data @ W_in^T + b_in (6-term bf16 MFMA) --------------
__global__ __launch_bounds__(256)
void z0_gemm(const float* __restrict__ X,      // [tc*NB][NI]
             const __bf16* __restrict__ Wi_t,  // 3 planes tiled KT=16
             const float* __restrict__ bias,
             float* __restrict__ Z0)           // [tc][NB*NH tiled] fp32
{
    const int tid = threadIdx.x;
    const int lane = tid & 63;
    const int w = tid >> 6;
    const int wm = w >> 1, wn = w & 1;
    const int m_base = blockIdx.y * 64 + wm * 32;
    const int n_base = blockIdx.x * 64 + wn * 32;
    const size_t PS = (size_t)NH * NI;

    f32x4 acc[2][2] = {};
    bf16x8 a1[2], a2[2], a3[2];

    for (int kt = 0; kt < 16; ++kt) {
        #pragma unroll
        for (int mt = 0; mt < 2; ++mt) {
            const int row = m_base + mt * 16 + (lane & 15);
            const float* src = X + (size_t)row * NI + kt * 32 + ((lane >> 4) << 3);
            float4 v0 = *reinterpret_cast<const float4*>(src);
            float4 v1 = *reinterpret_cast<const float4*>(src + 4);
            float xv[8] = {v0.x, v0.y, v0.z, v0.w, v1.x, v1.y, v1.z, v1.w};
            #pragma unroll
            for (int j = 0; j < 8; ++j) {
                float x = xv[j];
                __bf16 h1 = (__bf16)x;  float r1 = x - (float)h1;
                __bf16 h2 = (__bf16)r1; float r2 = r1 - (float)h2;
                __bf16 h3 = (__bf16)r2;
                a1[mt][j] = h1; a2[mt][j] = h2; a3[mt][j] = h3;
            }
        }
        #pragma unroll
        for (int nt = 0; nt < 2; ++nt) {
            const size_t bo = ((size_t)(((n_base >> 4) + nt) * 16 + kt) * 64 + lane) * 8;
            bf16x8 b1 = *reinterpret_cast<const bf16x8*>(Wi_t + bo);
            bf16x8 b2 = *reinterpret_cast<const bf16x8*>(Wi_t + PS + bo);
            bf16x8 b3 = *reinterpret_cast<const bf16x8*>(Wi_t + 2 * PS + bo);
            #pragma unroll
            for (int mt = 0; mt < 2; ++mt) {
                f32x4 A = acc[mt][nt];
                A = __builtin_amdgcn_mfma_f32_16x16x32_bf16(a1[mt], b1, A, 0, 0, 0);
                A = __builtin_amdgcn_mfma_f32_16x16x32_bf16(a1[mt], b2, A, 0, 0, 0);
                A = __builtin_amdgcn_mfma_f32_16x16x32_bf16(a2[mt], b1, A, 0, 0, 0);
                A = __builtin_amdgcn_mfma_f32_16x16x32_bf16(a2[mt], b2, A, 0, 0, 0);
                A = __builtin_amdgcn_mfma_f32_16x16x32_bf16(a1[mt], b3, A, 0, 0, 0);
                A = __builtin_amdgcn_mfma_f32_16x16x32_bf16(a3[mt], b1, A, 0, 0, 0);
                acc[mt][nt] = A;
            }
        }
    }

    const int c = lane & 15;
    const int r0 = (lane >> 4) * 4;
    #pragma unroll
    for (int nt = 0; nt < 2; ++nt) {
        const int n = n_base + nt * 16 + c;
        const float bi = bias[n];
        #pragma unroll
        for (int mt = 0; mt < 2; ++mt) {
            #pragma unroll
            for (int r = 0; r < 4; ++r) {
                const int m = m_base + mt * 16 + r0 + r;
                const int tl = m >> 9, b = m & 511;
                Z0[(size_t)tl * (NB * NH) + tiled_off(b, n, 32)] = acc[mt][nt][r] + bi;
            }
        }
    }
}

// ---------------- layer-0 sequential leaky over the whole chunk -------------
__global__ __launch_bounds__(256)
void leaky0_seq(const float* __restrict__ Z0,      // [tc][NB*NH tiled]
                __bf16* __restrict__ spk0_all,     // [tc][NB*NH tiled]
                float* __restrict__ mem0_g,        // [NB*NH tiled]
                const float* __restrict__ beta0,
                const float* __restrict__ thr0,
                int tc)
{
    const int g = blockIdx.x * 256 + threadIdx.x;    // 131072 threads
    const int i0 = g * 4;
    const int n0 = (((i0 >> 9) & 31) << 5) + (((i0 >> 7) & 3) << 3) + (i0 & 7);

    float4 mem = *reinterpret_cast<const float4*>(mem0_g + i0);
    float4 be  = *reinterpret_cast<const float4*>(beta0 + n0);
    float4 th  = *reinterpret_cast<const float4*>(thr0 + n0);

    for (int s = 0; s < tc; ++s) {
        float4 z = *reinterpret_cast<const float4*>(Z0 + (size_t)s * (NB * NH) + i0);
        bf16x4 sv;
        float mn, sp;
        leaky_upd(z.x, mem.x, be.x, th.x, mn, sp); mem.x = mn; sv[0] = (__bf16)sp;
        leaky_upd(z.y, mem.y, be.y, th.y, mn, sp); mem.y = mn; sv[1] = (__bf16)sp;
        leaky_upd(z.z, mem.z, be.z, th.z, mn, sp); mem.z = mn; sv[2] = (__bf16)sp;
        leaky_upd(z.w, mem.w, be.w, th.w, mn, sp); mem.w = mn; sv[3] = (__bf16)sp;
        *reinterpret_cast<bf16x4*>(spk0_all + (size_t)s * (NB * NH) + i0) = sv;
    }
    *reinterpret_cast<float4*>(mem0_g + i0) = mem;
}

// ---------------- grid barrier: flag stores + leader scan -------------------
__device__ __forceinline__ void gridbar(int* flags, int* gen, int target) {
    __syncthreads();
    if (threadIdx.x == 0) {
        __builtin_amdgcn_fence(__ATOMIC_RELEASE, "agent");
        __hip_atomic_store(&flags[blockIdx.x], target, __ATOMIC_RELAXED, __HIP_MEMORY_SCOPE_AGENT);
    }
    if (blockIdx.x == 0) {
        if (threadIdx.x < 64) {
            const int l = threadIdx.x;
            for (;;) {
                int v0 = __hip_atomic_load(&flags[l],       __ATOMIC_RELAXED, __HIP_MEMORY_SCOPE_AGENT);
                int v1 = __hip_atomic_load(&flags[l + 64],  __ATOMIC_RELAXED, __HIP_MEMORY_SCOPE_AGENT);
                int v2 = __hip_atomic_load(&flags[l + 128], __ATOMIC_RELAXED, __HIP_MEMORY_SCOPE_AGENT);
                int mn = min(min(v0, v1), v2);
                if (__all(mn >= target)) break;
                __builtin_amdgcn_s_sleep(1);
            }
        }
        __syncthreads();
        if (threadIdx.x == 0) {
            __builtin_amdgcn_fence(__ATOMIC_ACQ_REL, "agent");
            __hip_atomic_store(gen, target, __ATOMIC_RELAXED, __HIP_MEMORY_SCOPE_AGENT);
        }
    } else if (threadIdx.x == 0) {
        while (__hip_atomic_load(gen, __ATOMIC_RELAXED, __HIP_MEMORY_SCOPE_AGENT) < target)
            __builtin_amdgcn_s_sleep(2);
    }
    __syncthreads();
    __builtin_amdgcn_fence(__ATOMIC_ACQUIRE, "agent");
}

// ---------------- hidden-layer pipeline (persistent, NT-batched) ------------
__global__ __launch_bounds__(512, 1)
void snn_pipe(const __bf16* __restrict__ spk0_all,  // [tc][tiled]
              __bf16* __restrict__ spk3_all,        // [tc][tiled]
              const __bf16* __restrict__ Wt,
              const float* __restrict__ b_h,
              const float* __restrict__ beta_h,
              const float* __restrict__ thr_h,
              float* __restrict__ mem123,           // chunk-persist
              __bf16* __restrict__ spk1,            // 2*NT-slot ring
              __bf16* __restrict__ spk2,            // 2*NT-slot ring
              int* __restrict__ flags, int* __restrict__ gen,
              int tc)
{
    __shared__ __bf16 Wlds[3 * 32 * 512];   // 96 KB: all 3 planes, 16-col slice

    const int blk  = blockIdx.x;
    const int tid  = threadIdx.x;
    const int lane = tid & 63;
    const int w    = tid >> 6;              // 8 waves
    const int ell  = blk >> 6;              // layer 0..2
    const int ns   = blk & 63;              // 16-col slice

    // stage all 3 weight planes into LDS
    {
        const __bf16* Wsrc = Wt + (size_t)ell * 3 * (NH * NH) + (size_t)ns * 16384;
        #pragma unroll
        for (int p = 0; p < 3; ++p) {
            const bf16x8* src = reinterpret_cast<const bf16x8*>(Wsrc + (size_t)p * (NH * NH));
            bf16x8* dst = reinterpret_cast<bf16x8*>(Wlds + p * 16384);
            for (int i = tid; i < 2048; i += 512) dst[i] = src[i];
        }
    }

    // per-thread fixed output elements: col n, rows (w*4+i)*16 + r0 + r
    const int c  = lane & 15;
    const int r0 = (lane >> 4) * 4;
    const int n  = ns * 16 + c;
    float* memg = mem123 + (size_t)ell * (NB * NH);
    const float bi = b_h[ell * NH + n];
    const float be = beta_h[(ell + 1) * NH + n];
    const float th = thr_h[(ell + 1) * NH + n];

    float memr[16];
    #pragma unroll
    for (int i = 0; i < 4; ++i)
        #pragma unroll
        for (int r = 0; r < 4; ++r)
            memr[i * 4 + r] = memg[(size_t)((w * 4 + i) * 16 + r0 + r) * NH + n];

    const int st_col = ((n >> 5) << 9) + (((n >> 3) & 3) << 7) + (n & 7);
    const size_t SPKS = (size_t)NB * NH;
    const int G = (tc + NT - 1) / NT;

    __syncthreads();

    for (int p = 0; p < G + 2; ++p) {
        const int g = p - ell;
        if (g >= 0 && g < G) {
            const int sbase = g * NT;
            const int send  = (sbase + NT < tc) ? sbase + NT : tc;
            const int slot0 = (g & 1) * NT;
            for (int s = sbase; s < send; s += 2) {
                const int sp0 = slot0 + (s - sbase);
                const __bf16* X0 = (ell == 0) ? spk0_all + (size_t)s * SPKS
                                  : (ell == 1) ? spk1 + (size_t)sp0 * SPKS
                                               : spk2 + (size_t)sp0 * SPKS;
                __bf16* Y0 = (ell == 0) ? spk1 + (size_t)sp0 * SPKS
                            : (ell == 1) ? spk2 + (size_t)sp0 * SPKS
                                         : spk3_all + (size_t)s * SPKS;
                if (s + 1 < send) {
                    const __bf16* X1 = (ell == 0) ? spk0_all + (size_t)(s + 1) * SPKS
                                      : (ell == 1) ? spk1 + (size_t)(sp0 + 1) * SPKS
                                                   : spk2 + (size_t)(sp0 + 1) * SPKS;
                    __bf16* Y1 = (ell == 0) ? spk1 + (size_t)(sp0 + 1) * SPKS
                                : (ell == 1) ? spk2 + (size_t)(sp0 + 1) * SPKS
                                             : spk3_all + (size_t)(s + 1) * SPKS;

                    f32x4 acc0[4] = {}, acc1[4] = {};
                    for (int kt = 0; kt < 32; ++kt) {
                        const int lo = kt * 512 + lane * 8;
                        bf16x8 b1 = *reinterpret_cast<const bf16x8*>(Wlds + lo);
                        bf16x8 b2 = *reinterpret_cast<const bf16x8*>(Wlds + 16384 + lo);
                        bf16x8 b3 = *reinterpret_cast<const bf16x8*>(Wlds + 32768 + lo);
                        bf16x8 a0[4], a1v[4];
                        #pragma unroll
                        for (int i = 0; i < 4; ++i) {
                            const size_t ro = (size_t)(w * 4 + i) * 16384 + lo;
                            a0[i]  = *reinterpret_cast<const bf16x8*>(X0 + ro);
                            a1v[i] = *reinterpret_cast<const bf16x8*>(X1 + ro);
                        }
                        #pragma unroll
                        for (int i = 0; i < 4; ++i) {
                            acc0[i] = __builtin_amdgcn_mfma_f32_16x16x32_bf16(a0[i],  b1, acc0[i], 0, 0, 0);
                            acc1[i] = __builtin_amdgcn_mfma_f32_16x16x32_bf16(a1v[i], b1, acc1[i], 0, 0, 0);
                        }
                        #pragma unroll
                        for (int i = 0; i < 4; ++i) {
                            acc0[i] = __builtin_amdgcn_mfma_f32_16x16x32_bf16(a0[i],  b2, acc0[i], 0, 0, 0);
                            acc1[i] = __builtin_amdgcn_mfma_f32_16x16x32_bf16(a1v[i], b2, acc1[i], 0, 0, 0);
                        }
                        #pragma unroll
                        for (int i = 0; i < 4; ++i) {
                            acc0[i] = __builtin_amdgcn_mfma_f32_16x16x32_bf16(a0[i],  b3, acc0[i], 0, 0, 0);
                            acc1[i] = __builtin_amdgcn_mfma_f32_16x16x32_bf16(a1v[i], b3, acc1[i], 0, 0, 0);
                        }
                    }
                    #pragma unroll
                    for (int i = 0; i < 4; ++i) {
                        #pragma unroll
                        for (int r = 0; r < 4; ++r) {
                            float mn, sp;
                            leaky_upd(acc0[i][r] + bi, memr[i * 4 + r], be, th, mn, sp);
                            memr[i * 4 + r] = mn;
                            Y0[(size_t)(w * 4 + i) * 16384 + st_col + (size_t)(r0 + r) * 8] = (__bf16)sp;
                        }
                    }
                    #pragma unroll
                    for (int i = 0; i < 4; ++i) {
                        #pragma unroll
                        for (int r = 0; r < 4; ++r) {
                            float mn, sp;
                            leaky_upd(acc1[i][r] + bi, memr[i * 4 + r], be, th, mn, sp);
                            memr[i * 4 + r] = mn;
                            Y1[(size_t)(w * 4 + i) * 16384 + st_col + (size_t)(r0 + r) * 8] = (__bf16)sp;
                        }
                    }
                } else {
                    f32x4 acc[4] = {};
                    for (int kt = 0; kt < 32; ++kt) {
                        const int lo = kt * 512 + lane * 8;
                        bf16x8 b1 = *reinterpret_cast<const bf16x8*>(Wlds + lo);
                        bf16x8 b2 = *reinterpret_cast<const bf16x8*>(Wlds + 16384 + lo);
                        bf16x8 b3 = *reinterpret_cast<const bf16x8*>(Wlds + 32768 + lo);
                        bf16x8 a[4];
                        #pragma unroll
                        for (int i = 0; i < 4; ++i)
                            a[i] = *reinterpret_cast<const bf16x8*>(X0 + (size_t)(w * 4 + i) * 16384 + lo);
                        #pragma unroll
                        for (int i = 0; i < 4; ++i) {
                            acc[i] = __builtin_amdgcn_mfma_f32_16x16x32_bf16(a[i], b1, acc[i], 0, 0, 0);
                            acc[i] = __builtin_amdgcn_mfma_f32_16x16x32_bf16(a[i], b2, acc[i], 0, 0, 0);
                            acc[i] = __builtin_amdgcn_mfma_f32_16x16x32_bf16(a[i], b3, acc[i], 0, 0, 0);
                        }
                    }
                    #pragma unroll
                    for (int i = 0; i < 4; ++i) {
                        #pragma unroll
                        for (int r = 0; r < 4; ++r) {
                            float mn, sp;
                            leaky_upd(acc[i][r] + bi, memr[i * 4 + r], be, th, mn, sp);
                            memr[i * 4 + r] = mn;
                            Y0[(size_t)(w * 4 + i) * 16384 + st_col + (size_t)(r0 + r) * 8] = (__bf16)sp;
                        }
                    }
                }
            }
        }
        gridbar(flags, gen, p + 1);
    }

    #pragma unroll
    for (int i = 0; i < 4; ++i)
        #pragma unroll
        for (int r = 0; r < 4; ++r)
            memg[(size_t)((w * 4 + i) * 16 + r0 + r) * NH + n] = memr[i * 4 + r];
}

// ---------------- batched output GEMM over the chunk ------------------------
__global__ __launch_bounds__(256)
void zout_gemm(const __bf16* __restrict__ spk3_all,  // [tc][tiled]
               const __bf16* __restrict__ Wo_t,      // 3 planes, 48 rows
               const float* __restrict__ b_out,
               float* __restrict__ zout)             // [tc][512][48]
{
    const int s  = blockIdx.x >> 2;
    const int rg = blockIdx.x & 3;
    const int tid = threadIdx.x;
    const int lane = tid & 63;
    const int w = tid >> 6;                 // 4 waves, 2 row-tiles each
    const size_t PS = (size_t)48 * NH;
    const size_t SPKS = (size_t)NB * NH;

    f32x4 acc[2][3] = {};
    for (int kt = 0; kt < 32; ++kt) {
        const int lo = kt * 512 + lane * 8;
        bf16x8 a[2];
        #pragma unroll
        for (int i = 0; i < 2; ++i) {
            const int gmt = rg * 8 + w * 2 + i;
            a[i] = *reinterpret_cast<const bf16x8*>(spk3_all + s * SPKS + (size_t)gmt * 16384 + lo);
        }
        #pragma unroll
        for (int nt = 0; nt < 3; ++nt) {
            const size_t bo = (size_t)nt * 16384 + lo;
            bf16x8 b1 = *reinterpret_cast<const bf16x8*>(Wo_t + bo);
            bf16x8 b2 = *reinterpret_cast<const bf16x8*>(Wo_t + PS + bo);
            bf16x8 b3 = *reinterpret_cast<const bf16x8*>(Wo_t + 2 * PS + bo);
            #pragma unroll
            for (int i = 0; i < 2; ++i) {
                acc[i][nt] = __builtin_amdgcn_mfma_f32_16x16x32_bf16(a[i], b1, acc[i][nt], 0, 0, 0);
                acc[i][nt] = __builtin_amdgcn_mfma_f32_16x16x32_bf16(a[i], b2, acc[i][nt], 0, 0, 0);
                acc[i][nt] = __builtin_amdgcn_mfma_f32_16x16x32_bf16(a[i], b3, acc[i][nt], 0, 0, 0);
            }
        }
    }

    const int c = lane & 15, r0 = (lane >> 4) * 4;
    #pragma unroll
    for (int nt = 0; nt < 3; ++nt) {
        const int o = nt * 16 + c;
        if (o < NO) {
            const float bi = b_out[o];
            #pragma unroll
            for (int i = 0; i < 2; ++i) {
                #pragma unroll
                for (int r = 0; r < 4; ++r) {
                    const int b = (rg * 8 + w * 2 + i) * 16 + r0 + r;
                    zout[((size_t)s * NB + b) * 48 + o] = acc[i][nt][r] + bi;
                }
            }
        }
    }
}

// ---------------- sequential output leaky ------------------------------------
__global__ __launch_bounds__(256)
void out_seq(const float* __restrict__ zout,   // [tc][512][48]
             float* __restrict__ out,          // [TT][512][35]
             float* __restrict__ memo_g,       // [512*35]
             const float* __restrict__ beta_o,
             const float* __restrict__ thr_o,
             int t0, int tc)
{
    const int g = blockIdx.x * 256 + threadIdx.x;
    if (g >= NB * NO) return;
    const int b = g / NO;
    const int o = g - b * NO;
    float mem = memo_g[g];
    const float be = beta_o[o], th = thr_o[o];
    for (int s = 0; s < tc; ++s) {
        float z = zout[((size_t)s * NB + b) * 48 + o];
        float mn, sp;
        leaky_upd(z, mem, be, th, mn, sp);
        mem = mn;
        out[((size_t)(t0 + s) * NB + b) * NO + o] = sp;
    }
    memo_g[g] = mem;
}

// ---------------- launch ----------------------------------------------------
extern "C" void kernel_launch(void* const* d_in, const int* in_sizes, int n_in,
                              void* d_out, int out_size, void* d_ws, size_t ws_size,
                              hipStream_t stream) {
    const float* data   = (const float*)d_in[0];
    const float* W_in   = (const float*)d_in[1];
    const float* b_in   = (const float*)d_in[2];
    const float* W_h    = (const float*)d_in[3];
    const float* b_h    = (const float*)d_in[4];
    const float* W_out  = (const float*)d_in[5];
    const float* b_out  = (const float*)d_in[6];
    const float* beta_h = (const float*)d_in[7];
    const float* thr_h  = (const float*)d_in[8];
    const float* beta_o = (const float*)d_in[9];
    const float* thr_o  = (const float*)d_in[10];
    float* out = (float*)d_out;

    char* ws = (char*)d_ws;
    float*  mem123 = (float*)(ws + WS_MEM123);
    float*  mem0_g = (float*)(ws + WS_MEM0);
    float*  memo_g = (float*)(ws + WS_MEMO);
    int*    flags  = (int*)(ws + WS_FLAGS);
    int*    gen    = (int*)(ws + WS_GEN);
    __bf16* spk1   = (__bf16*)(ws + WS_SPK1);
    __bf16* spk2   = (__bf16*)(ws + WS_SPK2);
    __bf16* Wt     = (__bf16*)(ws + WS_WT);
    __bf16* Wi_t   = (__bf16*)(ws + WS_WIT);
    __bf16* Wo_t   = (__bf16*)(ws + WS_WOT);

    size_t avail = (ws_size > WS_DYN) ? (ws_size - WS_DYN) / STEP_BYTES : 1;
    int Tc = (int)(avail < 1 ? 1 : (avail > TT ? TT : avail));

    float*  zout     = (float*)(ws + WS_DYN);
    __bf16* spk0_all = (__bf16*)(ws + WS_DYN + (size_t)Tc * 98304u);
    char*   unionb   = ws + WS_DYN + (size_t)Tc * (98304u + 1048576u);
    float*  Z0       = (float*)unionb;            // [Tc][NB*NH] fp32
    __bf16* spk3_all = (__bf16*)unionb;           // [Tc][NB*NH] bf16 (after Z0 dead)

    hipMemsetAsync(ws, 0, WS_FLAGS, stream);      // mem123 + mem0 + memo
    split_weights<<<dim3(1536), dim3(256), 0, stream>>>(W_h, Wt);
    split_win<<<dim3(256), dim3(256), 0, stream>>>(W_in, Wi_t);
    split_wout<<<dim3(24), dim3(256), 0, stream>>>(W_out, Wo_t);

    for (int t0c = 0; t0c < TT; t0c += Tc) {
        const int tcc = (TT - t0c < Tc) ? (TT - t0c) : Tc;
        z0_gemm<<<dim3(NH / 64, tcc * (NB / 64)), dim3(256), 0, stream>>>(
            data + (size_t)t0c * NB * NI, Wi_t, b_in, Z0);
        leaky0_seq<<<dim3(512), dim3(256), 0, stream>>>(
            Z0, spk0_all, mem0_g, beta_h, thr_h, tcc);
        hipMemsetAsync(ws + WS_FLAGS, 0, 1280, stream);   // flags + gen
        snn_pipe<<<dim3(NBLK_P), dim3(512), 0, stream>>>(
            spk0_all, spk3_all, Wt, b_h, beta_h, thr_h,
            mem123, spk1, spk2, flags, gen, tcc);
        zout_gemm<<<dim3(tcc * 4), dim3(256), 0, stream>>>(
            spk3_all, Wo_t, b_out, zout);
        out_seq<<<dim3((NB * NO + 255) / 256), dim3(256), 0, stream>>>(
            zout, out, memo_g, beta_o, thr_o, t0c, tcc);
    }
}

// Round 8
// 2485.761 us; speedup vs baseline: 7.8846x; 1.0877x over previous
//
#include <hip/hip_runtime.h>
#include <hip/hip_bf16.h>

// SNN, 5 layers, T=100, B=512.  R8 = R7 + BIT-PACKED spikes everywhere.
//  - Inter-layer spikes stored as bits (64KB/step vs 1MB bf16): producer uses
//    __ballot (fragment-aligned), consumer expands byte->bf16x8 in VALU
//    (overlaps MFMA pipe). Kills the per-barrier L2-refetch bottleneck.
//  - snn_pipe: 192 blocks x 512 thr, 3-layer skewed pipeline, NT=8 steps/phase
//    (15 barriers), all 3 weight planes in LDS, membranes in registers,
//    one-kt-ahead prefetch of bit words.
//  - z0_gemm (fp32 Z0), leaky0_seq (bits out), zout_gemm (bits in), out_seq.

#define NB 512
#define NH 1024
#define NI 512
#define NO 35
#define TT 100
#define NBLK_P 192
#define NT 8

typedef __bf16 bf16x8 __attribute__((ext_vector_type(8)));
typedef float f32x4 __attribute__((ext_vector_type(4)));

// MFMA 16x16x32 operand tiling over [rows][K]: [row/16][k/32][lane][8],
// lane = (row&15) | (((k>>3)&3)<<4), elem j = k&7.  KT = K/32.
__device__ __forceinline__ size_t tiled_off(int row, int k, int KT) {
    return ((size_t)((row >> 4) * KT + (k >> 5)) * 64
            + (row & 15) + (((k >> 3) & 3) << 4)) * 8 + (k & 7);
}

// Bit frame per step: u32 word[(mt*32+kt)*16 + row]; bit b of word = k-bit
// kt*32+b for row (mt*16+row). 16384 u32 = 64KB per step.
#define BITFRAME 16384

__device__ __forceinline__ void leaky_upd(float zin, float mprev, float be, float th,
                                          float& mnew, float& spk) {
    float rs = (mprev - th > 0.0f) ? th : 0.0f;          // reset*thr (detached)
    float bc = fminf(fmaxf(be, 0.0f), 1.0f);             // clip(beta,0,1)
    mnew = bc * mprev + zin - rs;
    spk  = (mnew - th > 0.0f) ? 1.0f : 0.0f;
}

// byte (8 spike bits) -> 8 bf16 {0.0,1.0}; bit j -> elem j.
__device__ __forceinline__ bf16x8 expand_byte(unsigned int b) {
    union { unsigned int u[4]; bf16x8 v; } r;
    #pragma unroll
    for (int j = 0; j < 4; ++j) {
        unsigned int x = (b >> (2 * j)) & 3u;
        unsigned int y = (x | (x << 15)) & 0x00010001u;
        r.u[j] = (y << 14) - (y << 7);   // y * 0x3F80 (bf16 1.0)
    }
    return r.v;
}

// ---------------- ws layout (bytes) ----------------
#define WS_MEM123   0u           // 6,291,456 (mem L1..L3, chunk-persist)
#define WS_MEM0     6291456u     // 2,097,152 (layer-0 mem, tiled-linear fp32)
#define WS_MEMO     8388608u     // 71,680
#define WS_FLAGS    8460288u     // 1,024
#define WS_GEN      8461312u     // 256
#define WS_SPK1     8461568u     // ring1: 2*NT*64KB = 1,048,576
#define WS_SPK2     9510144u     // ring2: 1,048,576
#define WS_WT       10558720u    // 18,874,368 (W_h 3 layers x 3 planes tiled)
#define WS_WIT      29433088u    // 3,145,728  (W_in 3 planes, KT=16)
#define WS_WOT      32578816u    // 294,912    (W_out padded 48 rows, 3 planes)
#define WS_DYN      32873728u
// per step: zout 98,304 | spk0 bits 65,536 | union(Z0 fp32 2MB / spk3 bits 64KB)
#define STEP_BYTES  2260992u

// ---------------- weight splits (unchanged) ----------------
__global__ __launch_bounds__(256)
void split_weights(const float* __restrict__ W_h, __bf16* __restrict__ Wt) {
    const int id = blockIdx.x * 256 + threadIdx.x;
    const int layer = id >> 17;
    const int rem = id & 131071;
    const int n = rem >> 7;
    const int k0 = (rem & 127) << 3;
    const float* src = W_h + ((size_t)layer * NH + n) * NH + k0;
    __bf16* dst = Wt + (size_t)layer * 3 * NH * NH;
    const size_t PS = (size_t)NH * NH;
    const size_t off = tiled_off(n, k0, 32);
    bf16x8 p1, p2, p3;
    #pragma unroll
    for (int j = 0; j < 8; ++j) {
        float w = src[j];
        __bf16 a = (__bf16)w;  float r1 = w - (float)a;
        __bf16 b = (__bf16)r1; float r2 = r1 - (float)b;
        __bf16 c = (__bf16)r2;
        p1[j] = a; p2[j] = b; p3[j] = c;
    }
    *reinterpret_cast<bf16x8*>(dst + 0 * PS + off) = p1;
    *reinterpret_cast<bf16x8*>(dst + 1 * PS + off) = p2;
    *reinterpret_cast<bf16x8*>(dst + 2 * PS + off) = p3;
}

__global__ __launch_bounds__(256)
void split_win(const float* __restrict__ W_in, __bf16* __restrict__ Wi_t) {
    const int id = blockIdx.x * 256 + threadIdx.x;
    const int n = id >> 6;
    const int k0 = (id & 63) << 3;
    const float* src = W_in + (size_t)n * NI + k0;
    const size_t PS = (size_t)NH * NI;
    const size_t off = tiled_off(n, k0, 16);
    bf16x8 p1, p2, p3;
    #pragma unroll
    for (int j = 0; j < 8; ++j) {
        float w = src[j];
        __bf16 a = (__bf16)w;  float r1 = w - (float)a;
        __bf16 b = (__bf16)r1; float r2 = r1 - (float)b;
        __bf16 c = (__bf16)r2;
        p1[j] = a; p2[j] = b; p3[j] = c;
    }
    *reinterpret_cast<bf16x8*>(Wi_t + 0 * PS + off) = p1;
    *reinterpret_cast<bf16x8*>(Wi_t + 1 * PS + off) = p2;
    *reinterpret_cast<bf16x8*>(Wi_t + 2 * PS + off) = p3;
}

__global__ __launch_bounds__(256)
void split_wout(const float* __restrict__ W_out, __bf16* __restrict__ Wo_t) {
    const int id = blockIdx.x * 256 + threadIdx.x;
    if (id >= 48 * 128) return;
    const int o = id >> 7;
    const int k0 = (id & 127) << 3;
    const size_t PS = (size_t)48 * NH;
    const size_t off = tiled_off(o, k0, 32);
    bf16x8 p1 = {}, p2 = {}, p3 = {};
    if (o < NO) {
        const float* src = W_out + (size_t)o * NH + k0;
        #pragma unroll
        for (int j = 0; j < 8; ++j) {
            float w = src[j];
            __bf16 a = (__bf16)w;  float r1 = w - (float)a;
            __bf16 b = (__bf16)r1; float r2 = r1 - (float)b;
            __bf16 c = (__bf16)r2;
            p1[j] = a; p2[j] = b; p3[j] = c;
        }
    }
    *reinterpret_cast<bf16x8*>(Wo_t + 0 * PS + off) = p1;
    *reinterpret_cast<bf16x8*>(Wo_t + 1 * PS + off) = p2;
    *reinterpret_cast<bf16x8*>(Wo_t + 2 * PS + off) = p3;
}

// ---------------- Z0 = data @ W_in^T + b_in (6-term bf16 MFMA) --------------
__global__ __launch_bounds__(256)
void z0_gemm(const float* __restrict__ X,
             const __bf16* __restrict__ Wi_t,
             const float* __restrict__ bias,
             float* __restrict__ Z0)
{
    const int tid = threadIdx.x;
    const int lane = tid & 63;
    const int w = tid >> 6;
    const int wm = w >> 1, wn = w & 1;
    const int m_base = blockIdx.y * 64 + wm * 32;
    const int n_base = blockIdx.x * 64 + wn * 32;
    const size_t PS = (size_t)NH * NI;

    f32x4 acc[2][2] = {};
    bf16x8 a1[2], a2[2], a3[2];

    for (int kt = 0; kt < 16; ++kt) {
        #pragma unroll
        for (int mt = 0; mt < 2; ++mt) {
            const int row = m_base + mt * 16 + (lane & 15);
            const float* src = X + (size_t)row * NI + kt * 32 + ((lane >> 4) << 3);
            float4 v0 = *reinterpret_cast<const float4*>(src);
            float4 v1 = *reinterpret_cast<const float4*>(src + 4);
            float xv[8] = {v0.x, v0.y, v0.z, v0.w, v1.x, v1.y, v1.z, v1.w};
            #pragma unroll
            for (int j = 0; j < 8; ++j) {
                float x = xv[j];
                __bf16 h1 = (__bf16)x;  float r1 = x - (float)h1;
                __bf16 h2 = (__bf16)r1; float r2 = r1 - (float)h2;
                __bf16 h3 = (__bf16)r2;
                a1[mt][j] = h1; a2[mt][j] = h2; a3[mt][j] = h3;
            }
        }
        #pragma unroll
        for (int nt = 0; nt < 2; ++nt) {
            const size_t bo = ((size_t)(((n_base >> 4) + nt) * 16 + kt) * 64 + lane) * 8;
            bf16x8 b1 = *reinterpret_cast<const bf16x8*>(Wi_t + bo);
            bf16x8 b2 = *reinterpret_cast<const bf16x8*>(Wi_t + PS + bo);
            bf16x8 b3 = *reinterpret_cast<const bf16x8*>(Wi_t + 2 * PS + bo);
            #pragma unroll
            for (int mt = 0; mt < 2; ++mt) {
                f32x4 A = acc[mt][nt];
                A = __builtin_amdgcn_mfma_f32_16x16x32_bf16(a1[mt], b1, A, 0, 0, 0);
                A = __builtin_amdgcn_mfma_f32_16x16x32_bf16(a1[mt], b2, A, 0, 0, 0);
                A = __builtin_amdgcn_mfma_f32_16x16x32_bf16(a2[mt], b1, A, 0, 0, 0);
                A = __builtin_amdgcn_mfma_f32_16x16x32_bf16(a2[mt], b2, A, 0, 0, 0);
                A = __builtin_amdgcn_mfma_f32_16x16x32_bf16(a1[mt], b3, A, 0, 0, 0);
                A = __builtin_amdgcn_mfma_f32_16x16x32_bf16(a3[mt], b1, A, 0, 0, 0);
                acc[mt][nt] = A;
            }
        }
    }

    const int c = lane & 15;
    const int r0 = (lane >> 4) * 4;
    #pragma unroll
    for (int nt = 0; nt < 2; ++nt) {
        const int n = n_base + nt * 16 + c;
        const float bi = bias[n];
        #pragma unroll
        for (int mt = 0; mt < 2; ++mt) {
            #pragma unroll
            for (int r = 0; r < 4; ++r) {
                const int m = m_base + mt * 16 + r0 + r;
                const int tl = m >> 9, b = m & 511;
                Z0[(size_t)tl * (NB * NH) + tiled_off(b, n, 32)] = acc[mt][nt][r] + bi;
            }
        }
    }
}

// ---------------- layer-0 sequential leaky, BIT output ----------------------
__global__ __launch_bounds__(256)
void leaky0_seq(const float* __restrict__ Z0,          // [tc][NB*NH tiled]
                unsigned char* __restrict__ spk0b,     // [tc][64KB bit frames]
                float* __restrict__ mem0_g,
                const float* __restrict__ beta0,
                const float* __restrict__ thr0,
                int tc)
{
    const int f = blockIdx.x * 256 + threadIdx.x;   // 65536 fragments
    const int i0 = f * 8;
    const int mt = f >> 11;
    const int ktl = (f >> 6) & 31;
    const int lane = f & 63;
    const int row = lane & 15;
    const int byt = lane >> 4;
    const int n8 = ktl * 32 + byt * 8;
    const size_t bidx = ((size_t)(mt * 32 + ktl) * 16 + row) * 4 + byt;

    float m[8], be[8], th[8];
    #pragma unroll
    for (int j = 0; j < 8; ++j) {
        m[j]  = mem0_g[i0 + j];
        be[j] = beta0[n8 + j];
        th[j] = thr0[n8 + j];
    }

    for (int s = 0; s < tc; ++s) {
        const float* zp = Z0 + (size_t)s * (NB * NH) + i0;
        unsigned int b = 0;
        #pragma unroll
        for (int j = 0; j < 8; ++j) {
            float mn, sp;
            leaky_upd(zp[j], m[j], be[j], th[j], mn, sp);
            m[j] = mn;
            b |= (sp != 0.0f ? 1u : 0u) << j;
        }
        spk0b[(size_t)s * 65536 + bidx] = (unsigned char)b;
    }
    #pragma unroll
    for (int j = 0; j < 8; ++j) mem0_g[i0 + j] = m[j];
}

// ---------------- grid barrier: flag stores + leader scan -------------------
__device__ __forceinline__ void gridbar(int* flags, int* gen, int target) {
    __syncthreads();
    if (threadIdx.x == 0) {
        __builtin_amdgcn_fence(__ATOMIC_RELEASE, "agent");
        __hip_atomic_store(&flags[blockIdx.x], target, __ATOMIC_RELAXED, __HIP_MEMORY_SCOPE_AGENT);
    }
    if (blockIdx.x == 0) {
        if (threadIdx.x < 64) {
            const int l = threadIdx.x;
            for (;;) {
                int v0 = __hip_atomic_load(&flags[l],       __ATOMIC_RELAXED, __HIP_MEMORY_SCOPE_AGENT);
                int v1 = __hip_atomic_load(&flags[l + 64],  __ATOMIC_RELAXED, __HIP_MEMORY_SCOPE_AGENT);
                int v2 = __hip_atomic_load(&flags[l + 128], __ATOMIC_RELAXED, __HIP_MEMORY_SCOPE_AGENT);
                int mn = min(min(v0, v1), v2);
                if (__all(mn >= target)) break;
                __builtin_amdgcn_s_sleep(1);
            }
        }
        __syncthreads();
        if (threadIdx.x == 0) {
            __builtin_amdgcn_fence(__ATOMIC_ACQ_REL, "agent");
            __hip_atomic_store(gen, target, __ATOMIC_RELAXED, __HIP_MEMORY_SCOPE_AGENT);
        }
    } else if (threadIdx.x == 0) {
        while (__hip_atomic_load(gen, __ATOMIC_RELAXED, __HIP_MEMORY_SCOPE_AGENT) < target)
            __builtin_amdgcn_s_sleep(2);
    }
    __syncthreads();
    __builtin_amdgcn_fence(__ATOMIC_ACQUIRE, "agent");
}

// ---------------- hidden-layer pipeline (persistent, bits in/out) -----------
__global__ __launch_bounds__(512, 1)
void snn_pipe(const unsigned int* __restrict__ spk0w,  // [tc] bit frames
              unsigned int* __restrict__ spk3w,        // [tc] bit frames
              const __bf16* __restrict__ Wt,
              const float* __restrict__ b_h,
              const float* __restrict__ beta_h,
              const float* __restrict__ thr_h,
              float* __restrict__ mem123,
              unsigned int* __restrict__ ring1,        // 2*NT frames
              unsigned int* __restrict__ ring2,
              int* __restrict__ flags, int* __restrict__ gen,
              int tc)
{
    __shared__ __bf16 Wlds[3 * 32 * 512];   // 96 KB

    const int blk  = blockIdx.x;
    const int tid  = threadIdx.x;
    const int lane = tid & 63;
    const int w    = tid >> 6;              // 8 waves
    const int ell  = blk >> 6;
    const int ns   = blk & 63;

    {
        const __bf16* Wsrc = Wt + (size_t)ell * 3 * (NH * NH) + (size_t)ns * 16384;
        #pragma unroll
        for (int p = 0; p < 3; ++p) {
            const bf16x8* src = reinterpret_cast<const bf16x8*>(Wsrc + (size_t)p * (NH * NH));
            bf16x8* dst = reinterpret_cast<bf16x8*>(Wlds + p * 16384);
            for (int i = tid; i < 2048; i += 512) dst[i] = src[i];
        }
    }

    const int c   = lane & 15;
    const int r0  = (lane >> 4) * 4;
    const int n   = ns * 16 + c;
    const int row = lane & 15;
    const int sh  = (lane >> 4) * 8;
    const int half = ns & 1;
    const int ktout = ns >> 1;

    float* memg = mem123 + (size_t)ell * (NB * NH);
    const float bi = b_h[ell * NH + n];
    const float be = beta_h[(ell + 1) * NH + n];
    const float th = thr_h[(ell + 1) * NH + n];

    float memr[16];
    #pragma unroll
    for (int i = 0; i < 4; ++i)
        #pragma unroll
        for (int r = 0; r < 4; ++r)
            memr[i * 4 + r] = memg[(size_t)((w * 4 + i) * 16 + r0 + r) * NH + n];

    const int G = (tc + NT - 1) / NT;

    __syncthreads();

    for (int p = 0; p < G + 2; ++p) {
        const int g = p - ell;
        if (g >= 0 && g < G) {
            const int sbase = g * NT;
            const int send  = (sbase + NT < tc) ? sbase + NT : tc;
            const int slot0 = (g & 1) * NT;
            for (int s = sbase; s < send; s += 2) {
                const int sl = slot0 + (s - sbase);
                const unsigned int* X0w = (ell == 0) ? spk0w + (size_t)s * BITFRAME
                                        : ((ell == 1) ? ring1 : ring2) + (size_t)sl * BITFRAME;
                unsigned short* Y0h = (unsigned short*)(
                    (ell == 2) ? spk3w + (size_t)s * BITFRAME
                               : ((ell == 0) ? ring1 : ring2) + (size_t)sl * BITFRAME);

                const bool pair = (s + 1 < send);
                const unsigned int* X1w = pair ?
                    ((ell == 0) ? spk0w + (size_t)(s + 1) * BITFRAME
                                : ((ell == 1) ? ring1 : ring2) + (size_t)(sl + 1) * BITFRAME)
                    : X0w;
                unsigned short* Y1h = pair ? (unsigned short*)(
                    (ell == 2) ? spk3w + (size_t)(s + 1) * BITFRAME
                               : ((ell == 0) ? ring1 : ring2) + (size_t)(sl + 1) * BITFRAME)
                    : Y0h;

                f32x4 acc0[4] = {}, acc1[4] = {};
                unsigned int bw0[4], bw1[4];
                #pragma unroll
                for (int i = 0; i < 4; ++i) {
                    const int wi = ((w * 4 + i) * 32 + 0) * 16 + row;
                    bw0[i] = X0w[wi];
                    bw1[i] = X1w[wi];
                }

                for (int kt = 0; kt < 32; ++kt) {
                    unsigned int nw0[4], nw1[4];
                    if (kt < 31) {
                        #pragma unroll
                        for (int i = 0; i < 4; ++i) {
                            const int wi = ((w * 4 + i) * 32 + kt + 1) * 16 + row;
                            nw0[i] = X0w[wi];
                            nw1[i] = X1w[wi];
                        }
                    }
                    const int lo = kt * 512 + lane * 8;
                    bf16x8 b1 = *reinterpret_cast<const bf16x8*>(Wlds + lo);
                    bf16x8 b2 = *reinterpret_cast<const bf16x8*>(Wlds + 16384 + lo);
                    bf16x8 b3 = *reinterpret_cast<const bf16x8*>(Wlds + 32768 + lo);
                    #pragma unroll
                    for (int i = 0; i < 4; ++i) {
                        bf16x8 a0 = expand_byte((bw0[i] >> sh) & 0xffu);
                        acc0[i] = __builtin_amdgcn_mfma_f32_16x16x32_bf16(a0, b1, acc0[i], 0, 0, 0);
                        acc0[i] = __builtin_amdgcn_mfma_f32_16x16x32_bf16(a0, b2, acc0[i], 0, 0, 0);
                        acc0[i] = __builtin_amdgcn_mfma_f32_16x16x32_bf16(a0, b3, acc0[i], 0, 0, 0);
                    }
                    if (pair) {
                        #pragma unroll
                        for (int i = 0; i < 4; ++i) {
                            bf16x8 a1 = expand_byte((bw1[i] >> sh) & 0xffu);
                            acc1[i] = __builtin_amdgcn_mfma_f32_16x16x32_bf16(a1, b1, acc1[i], 0, 0, 0);
                            acc1[i] = __builtin_amdgcn_mfma_f32_16x16x32_bf16(a1, b2, acc1[i], 0, 0, 0);
                            acc1[i] = __builtin_amdgcn_mfma_f32_16x16x32_bf16(a1, b3, acc1[i], 0, 0, 0);
                        }
                    }
                    #pragma unroll
                    for (int i = 0; i < 4; ++i) { bw0[i] = nw0[i]; bw1[i] = nw1[i]; }
                }

                // epilogue step s
                #pragma unroll
                for (int i = 0; i < 4; ++i) {
                    #pragma unroll
                    for (int r = 0; r < 4; ++r) {
                        float mn, sp;
                        leaky_upd(acc0[i][r] + bi, memr[i * 4 + r], be, th, mn, sp);
                        memr[i * 4 + r] = mn;
                        unsigned long long bal = __ballot(sp != 0.0f);
                        if ((lane & 15) == 0) {
                            const int rr = (lane >> 4) * 4 + r;
                            Y0h[(((w * 4 + i) * 32 + ktout) * 16 + rr) * 2 + half] =
                                (unsigned short)((bal >> ((lane >> 4) * 16)) & 0xFFFFu);
                        }
                    }
                }
                if (pair) {
                    #pragma unroll
                    for (int i = 0; i < 4; ++i) {
                        #pragma unroll
                        for (int r = 0; r < 4; ++r) {
                            float mn, sp;
                            leaky_upd(acc1[i][r] + bi, memr[i * 4 + r], be, th, mn, sp);
                            memr[i * 4 + r] = mn;
                            unsigned long long bal = __ballot(sp != 0.0f);
                            if ((lane & 15) == 0) {
                                const int rr = (lane >> 4) * 4 + r;
                                Y1h[(((w * 4 + i) * 32 + ktout) * 16 + rr) * 2 + half] =
                                    (unsigned short)((bal >> ((lane >> 4) * 16)) & 0xFFFFu);
                            }
                        }
                    }
                }
            }
        }
        gridbar(flags, gen, p + 1);
    }

    #pragma unroll
    for (int i = 0; i < 4; ++i)
        #pragma unroll
        for (int r = 0; r < 4; ++r)
            memg[(size_t)((w * 4 + i) * 16 + r0 + r) * NH + n] = memr[i * 4 + r];
}

// ---------------- batched output GEMM over the chunk (bits in) --------------
__global__ __launch_bounds__(256)
void zout_gemm(const unsigned int* __restrict__ spk3w,  // [tc] bit frames
               const __bf16* __restrict__ Wo_t,
               const float* __restrict__ b_out,
               float* __restrict__ zout)                // [tc][512][48]
{
    const int s  = blockIdx.x >> 2;
    const int rg = blockIdx.x & 3;
    const int tid = threadIdx.x;
    const int lane = tid & 63;
    const int w = tid >> 6;
    const int row = lane & 15;
    const int sh = (lane >> 4) * 8;
    const size_t PS = (size_t)48 * NH;
    const unsigned int* Xw = spk3w + (size_t)s * BITFRAME;

    f32x4 acc[2][3] = {};
    for (int kt = 0; kt < 32; ++kt) {
        const int lo = kt * 512 + lane * 8;
        bf16x8 a[2];
        #pragma unroll
        for (int i = 0; i < 2; ++i) {
            const int gmt = rg * 8 + w * 2 + i;
            unsigned int bw = Xw[(gmt * 32 + kt) * 16 + row];
            a[i] = expand_byte((bw >> sh) & 0xffu);
        }
        #pragma unroll
        for (int nt = 0; nt < 3; ++nt) {
            const size_t bo = (size_t)nt * 16384 + lo;
            bf16x8 b1 = *reinterpret_cast<const bf16x8*>(Wo_t + bo);
            bf16x8 b2 = *reinterpret_cast<const bf16x8*>(Wo_t + PS + bo);
            bf16x8 b3 = *reinterpret_cast<const bf16x8*>(Wo_t + 2 * PS + bo);
            #pragma unroll
            for (int i = 0; i < 2; ++i) {
                acc[i][nt] = __builtin_amdgcn_mfma_f32_16x16x32_bf16(a[i], b1, acc[i][nt], 0, 0, 0);
                acc[i][nt] = __builtin_amdgcn_mfma_f32_16x16x32_bf16(a[i], b2, acc[i][nt], 0, 0, 0);
                acc[i][nt] = __builtin_amdgcn_mfma_f32_16x16x32_bf16(a[i], b3, acc[i][nt], 0, 0, 0);
            }
        }
    }

    const int cc = lane & 15, rr0 = (lane >> 4) * 4;
    #pragma unroll
    for (int nt = 0; nt < 3; ++nt) {
        const int o = nt * 16 + cc;
        if (o < NO) {
            const float bi = b_out[o];
            #pragma unroll
            for (int i = 0; i < 2; ++i) {
                #pragma unroll
                for (int r = 0; r < 4; ++r) {
                    const int b = (rg * 8 + w * 2 + i) * 16 + rr0 + r;
                    zout[((size_t)s * NB + b) * 48 + o] = acc[i][nt][r] + bi;
                }
            }
        }
    }
}

// ---------------- sequential output leaky ------------------------------------
__global__ __launch_bounds__(256)
void out_seq(const float* __restrict__ zout,
             float* __restrict__ out,
             float* __restrict__ memo_g,
             const float* __restrict__ beta_o,
             const float* __restrict__ thr_o,
             int t0, int tc)
{
    const int g = blockIdx.x * 256 + threadIdx.x;
    if (g >= NB * NO) return;
    const int b = g / NO;
    const int o = g - b * NO;
    float mem = memo_g[g];
    const float be = beta_o[o], th = thr_o[o];
    for (int s = 0; s < tc; ++s) {
        float z = zout[((size_t)s * NB + b) * 48 + o];
        float mn, sp;
        leaky_upd(z, mem, be, th, mn, sp);
        mem = mn;
        out[((size_t)(t0 + s) * NB + b) * NO + o] = sp;
    }
    memo_g[g] = mem;
}

// ---------------- launch ----------------------------------------------------
extern "C" void kernel_launch(void* const* d_in, const int* in_sizes, int n_in,
                              void* d_out, int out_size, void* d_ws, size_t ws_size,
                              hipStream_t stream) {
    const float* data   = (const float*)d_in[0];
    const float* W_in   = (const float*)d_in[1];
    const float* b_in   = (const float*)d_in[2];
    const float* W_h    = (const float*)d_in[3];
    const float* b_h    = (const float*)d_in[4];
    const float* W_out  = (const float*)d_in[5];
    const float* b_out  = (const float*)d_in[6];
    const float* beta_h = (const float*)d_in[7];
    const float* thr_h  = (const float*)d_in[8];
    const float* beta_o = (const float*)d_in[9];
    const float* thr_o  = (const float*)d_in[10];
    float* out = (float*)d_out;

    char* ws = (char*)d_ws;
    float*        mem123 = (float*)(ws + WS_MEM123);
    float*        mem0_g = (float*)(ws + WS_MEM0);
    float*        memo_g = (float*)(ws + WS_MEMO);
    int*          flags  = (int*)(ws + WS_FLAGS);
    int*          gen    = (int*)(ws + WS_GEN);
    unsigned int* ring1  = (unsigned int*)(ws + WS_SPK1);
    unsigned int* ring2  = (unsigned int*)(ws + WS_SPK2);
    __bf16*       Wt     = (__bf16*)(ws + WS_WT);
    __bf16*       Wi_t   = (__bf16*)(ws + WS_WIT);
    __bf16*       Wo_t   = (__bf16*)(ws + WS_WOT);

    size_t avail = (ws_size > WS_DYN) ? (ws_size - WS_DYN) / STEP_BYTES : 1;
    int Tc = (int)(avail < 1 ? 1 : (avail > TT ? TT : avail));

    float*         zout  = (float*)(ws + WS_DYN);
    unsigned char* spk0b = (unsigned char*)(ws + WS_DYN + (size_t)Tc * 98304u);
    char*          unionb = ws + WS_DYN + (size_t)Tc * (98304u + 65536u);
    float*         Z0    = (float*)unionb;
    unsigned int*  spk3w = (unsigned int*)unionb;

    hipMemsetAsync(ws, 0, WS_FLAGS, stream);      // mem123 + mem0 + memo
    split_weights<<<dim3(1536), dim3(256), 0, stream>>>(W_h, Wt);
    split_win<<<dim3(256), dim3(256), 0, stream>>>(W_in, Wi_t);
    split_wout<<<dim3(24), dim3(256), 0, stream>>>(W_out, Wo_t);

    for (int t0c = 0; t0c < TT; t0c += Tc) {
        const int tcc = (TT - t0c < Tc) ? (TT - t0c) : Tc;
        z0_gemm<<<dim3(NH / 64, tcc * (NB / 64)), dim3(256), 0, stream>>>(
            data + (size_t)t0c * NB * NI, Wi_t, b_in, Z0);
        leaky0_seq<<<dim3(256), dim3(256), 0, stream>>>(
            Z0, spk0b, mem0_g, beta_h, thr_h, tcc);
        hipMemsetAsync(ws + WS_FLAGS, 0, 1280, stream);   // flags + gen
        snn_pipe<<<dim3(NBLK_P), dim3(512), 0, stream>>>(
            (const unsigned int*)spk0b, spk3w, Wt, b_h, beta_h, thr_h,
            mem123, ring1, ring2, flags, gen, tcc);
        zout_gemm<<<dim3(tcc * 4), dim3(256), 0, stream>>>(
            spk3w, Wo_t, b_out, zout);
        out_seq<<<dim3((NB * NO + 255) / 256), dim3(256), 0, stream>>>(
            zout, out, memo_g, beta_o, thr_o, t0c, tcc);
    }
}

// Round 9
// 1904.555 us; speedup vs baseline: 10.2907x; 1.3052x over previous
//
#include <hip/hip_runtime.h>
#include <hip/hip_bf16.h>

// SNN, 5 layers, T=100, B=512.  R9 = R8 + LUT-based bit->bf16 expansion (LDS)
// + 32col x 256row hidden blocks (2x A-frag reuse, planes 1+2 in LDS 128KB,
// plane 3 streamed with prefetch).  Everything else as R8.

#define NB 512
#define NH 1024
#define NI 512
#define NO 35
#define TT 100
#define NBLK_P 192
#define NT 8

typedef __bf16 bf16x8 __attribute__((ext_vector_type(8)));
typedef float f32x4 __attribute__((ext_vector_type(4)));

__device__ __forceinline__ size_t tiled_off(int row, int k, int KT) {
    return ((size_t)((row >> 4) * KT + (k >> 5)) * 64
            + (row & 15) + (((k >> 3) & 3) << 4)) * 8 + (k & 7);
}

#define BITFRAME 16384   // u32 words per step frame (64KB)

__device__ __forceinline__ void leaky_upd(float zin, float mprev, float be, float th,
                                          float& mnew, float& spk) {
    float rs = (mprev - th > 0.0f) ? th : 0.0f;
    float bc = fminf(fmaxf(be, 0.0f), 1.0f);
    mnew = bc * mprev + zin - rs;
    spk  = (mnew - th > 0.0f) ? 1.0f : 0.0f;
}

// byte (8 spike bits) -> 8 bf16 {0.0,1.0} (VALU version, used off-pipe)
__device__ __forceinline__ bf16x8 expand_byte(unsigned int b) {
    union { unsigned int u[4]; bf16x8 v; } r;
    #pragma unroll
    for (int j = 0; j < 4; ++j) {
        unsigned int x = (b >> (2 * j)) & 3u;
        unsigned int y = (x | (x << 15)) & 0x00010001u;
        r.u[j] = (y << 14) - (y << 7);
    }
    return r.v;
}

// ---------------- ws layout (bytes) ----------------
#define WS_MEM123   0u
#define WS_MEM0     6291456u
#define WS_MEMO     8388608u
#define WS_FLAGS    8460288u
#define WS_GEN      8461312u
#define WS_SPK1     8461568u     // ring1: 2*NT*64KB = 1,048,576
#define WS_SPK2     9510144u
#define WS_WT       10558720u    // 18,874,368
#define WS_WIT      29433088u    // 3,145,728
#define WS_WOT      32578816u    // 294,912
#define WS_DYN      32873728u
#define STEP_BYTES  2260992u

// ---------------- weight splits (unchanged) ----------------
__global__ __launch_bounds__(256)
void split_weights(const float* __restrict__ W_h, __bf16* __restrict__ Wt) {
    const int id = blockIdx.x * 256 + threadIdx.x;
    const int layer = id >> 17;
    const int rem = id & 131071;
    const int n = rem >> 7;
    const int k0 = (rem & 127) << 3;
    const float* src = W_h + ((size_t)layer * NH + n) * NH + k0;
    __bf16* dst = Wt + (size_t)layer * 3 * NH * NH;
    const size_t PS = (size_t)NH * NH;
    const size_t off = tiled_off(n, k0, 32);
    bf16x8 p1, p2, p3;
    #pragma unroll
    for (int j = 0; j < 8; ++j) {
        float w = src[j];
        __bf16 a = (__bf16)w;  float r1 = w - (float)a;
        __bf16 b = (__bf16)r1; float r2 = r1 - (float)b;
        __bf16 c = (__bf16)r2;
        p1[j] = a; p2[j] = b; p3[j] = c;
    }
    *reinterpret_cast<bf16x8*>(dst + 0 * PS + off) = p1;
    *reinterpret_cast<bf16x8*>(dst + 1 * PS + off) = p2;
    *reinterpret_cast<bf16x8*>(dst + 2 * PS + off) = p3;
}

__global__ __launch_bounds__(256)
void split_win(const float* __restrict__ W_in, __bf16* __restrict__ Wi_t) {
    const int id = blockIdx.x * 256 + threadIdx.x;
    const int n = id >> 6;
    const int k0 = (id & 63) << 3;
    const float* src = W_in + (size_t)n * NI + k0;
    const size_t PS = (size_t)NH * NI;
    const size_t off = tiled_off(n, k0, 16);
    bf16x8 p1, p2, p3;
    #pragma unroll
    for (int j = 0; j < 8; ++j) {
        float w = src[j];
        __bf16 a = (__bf16)w;  float r1 = w - (float)a;
        __bf16 b = (__bf16)r1; float r2 = r1 - (float)b;
        __bf16 c = (__bf16)r2;
        p1[j] = a; p2[j] = b; p3[j] = c;
    }
    *reinterpret_cast<bf16x8*>(Wi_t + 0 * PS + off) = p1;
    *reinterpret_cast<bf16x8*>(Wi_t + 1 * PS + off) = p2;
    *reinterpret_cast<bf16x8*>(Wi_t + 2 * PS + off) = p3;
}

__global__ __launch_bounds__(256)
void split_wout(const float* __restrict__ W_out, __bf16* __restrict__ Wo_t) {
    const int id = blockIdx.x * 256 + threadIdx.x;
    if (id >= 48 * 128) return;
    const int o = id >> 7;
    const int k0 = (id & 127) << 3;
    const size_t PS = (size_t)48 * NH;
    const size_t off = tiled_off(o, k0, 32);
    bf16x8 p1 = {}, p2 = {}, p3 = {};
    if (o < NO) {
        const float* src = W_out + (size_t)o * NH + k0;
        #pragma unroll
        for (int j = 0; j < 8; ++j) {
            float w = src[j];
            __bf16 a = (__bf16)w;  float r1 = w - (float)a;
            __bf16 b = (__bf16)r1; float r2 = r1 - (float)b;
            __bf16 c = (__bf16)r2;
            p1[j] = a; p2[j] = b; p3[j] = c;
        }
    }
    *reinterpret_cast<bf16x8*>(Wo_t + 0 * PS + off) = p1;
    *reinterpret_cast<bf16x8*>(Wo_t + 1 * PS + off) = p2;
    *reinterpret_cast<bf16x8*>(Wo_t + 2 * PS + off) = p3;
}

// ---------------- Z0 = data @ W_in^T + b_in (6-term bf16 MFMA) --------------
__global__ __launch_bounds__(256)
void z0_gemm(const float* __restrict__ X,
             const __bf16* __restrict__ Wi_t,
             const float* __restrict__ bias,
             float* __restrict__ Z0)
{
    const int tid = threadIdx.x;
    const int lane = tid & 63;
    const int w = tid >> 6;
    const int wm = w >> 1, wn = w & 1;
    const int m_base = blockIdx.y * 64 + wm * 32;
    const int n_base = blockIdx.x * 64 + wn * 32;
    const size_t PS = (size_t)NH * NI;

    f32x4 acc[2][2] = {};
    bf16x8 a1[2], a2[2], a3[2];

    for (int kt = 0; kt < 16; ++kt) {
        #pragma unroll
        for (int mt = 0; mt < 2; ++mt) {
            const int row = m_base + mt * 16 + (lane & 15);
            const float* src = X + (size_t)row * NI + kt * 32 + ((lane >> 4) << 3);
            float4 v0 = *reinterpret_cast<const float4*>(src);
            float4 v1 = *reinterpret_cast<const float4*>(src + 4);
            float xv[8] = {v0.x, v0.y, v0.z, v0.w, v1.x, v1.y, v1.z, v1.w};
            #pragma unroll
            for (int j = 0; j < 8; ++j) {
                float x = xv[j];
                __bf16 h1 = (__bf16)x;  float r1 = x - (float)h1;
                __bf16 h2 = (__bf16)r1; float r2 = r1 - (float)h2;
                __bf16 h3 = (__bf16)r2;
                a1[mt][j] = h1; a2[mt][j] = h2; a3[mt][j] = h3;
            }
        }
        #pragma unroll
        for (int nt = 0; nt < 2; ++nt) {
            const size_t bo = ((size_t)(((n_base >> 4) + nt) * 16 + kt) * 64 + lane) * 8;
            bf16x8 b1 = *reinterpret_cast<const bf16x8*>(Wi_t + bo);
            bf16x8 b2 = *reinterpret_cast<const bf16x8*>(Wi_t + PS + bo);
            bf16x8 b3 = *reinterpret_cast<const bf16x8*>(Wi_t + 2 * PS + bo);
            #pragma unroll
            for (int mt = 0; mt < 2; ++mt) {
                f32x4 A = acc[mt][nt];
                A = __builtin_amdgcn_mfma_f32_16x16x32_bf16(a1[mt], b1, A, 0, 0, 0);
                A = __builtin_amdgcn_mfma_f32_16x16x32_bf16(a1[mt], b2, A, 0, 0, 0);
                A = __builtin_amdgcn_mfma_f32_16x16x32_bf16(a2[mt], b1, A, 0, 0, 0);
                A = __builtin_amdgcn_mfma_f32_16x16x32_bf16(a2[mt], b2, A, 0, 0, 0);
                A = __builtin_amdgcn_mfma_f32_16x16x32_bf16(a1[mt], b3, A, 0, 0, 0);
                A = __builtin_amdgcn_mfma_f32_16x16x32_bf16(a3[mt], b1, A, 0, 0, 0);
                acc[mt][nt] = A;
            }
        }
    }

    const int c = lane & 15;
    const int r0 = (lane >> 4) * 4;
    #pragma unroll
    for (int nt = 0; nt < 2; ++nt) {
        const int n = n_base + nt * 16 + c;
        const float bi = bias[n];
        #pragma unroll
        for (int mt = 0; mt < 2; ++mt) {
            #pragma unroll
            for (int r = 0; r < 4; ++r) {
                const int m = m_base + mt * 16 + r0 + r;
                const int tl = m >> 9, b = m & 511;
                Z0[(size_t)tl * (NB * NH) + tiled_off(b, n, 32)] = acc[mt][nt][r] + bi;
            }
        }
    }
}

// ---------------- layer-0 sequential leaky, BIT output ----------------------
__global__ __launch_bounds__(256)
void leaky0_seq(const float* __restrict__ Z0,
                unsigned char* __restrict__ spk0b,
                float* __restrict__ mem0_g,
                const float* __restrict__ beta0,
                const float* __restrict__ thr0,
                int tc)
{
    const int f = blockIdx.x * 256 + threadIdx.x;
    const int i0 = f * 8;
    const int mt = f >> 11;
    const int ktl = (f >> 6) & 31;
    const int lane = f & 63;
    const int row = lane & 15;
    const int byt = lane >> 4;
    const int n8 = ktl * 32 + byt * 8;
    const size_t bidx = ((size_t)(mt * 32 + ktl) * 16 + row) * 4 + byt;

    float m[8], be[8], th[8];
    #pragma unroll
    for (int j = 0; j < 8; ++j) {
        m[j]  = mem0_g[i0 + j];
        be[j] = beta0[n8 + j];
        th[j] = thr0[n8 + j];
    }

    for (int s = 0; s < tc; ++s) {
        const float* zp = Z0 + (size_t)s * (NB * NH) + i0;
        unsigned int b = 0;
        #pragma unroll
        for (int j = 0; j < 8; ++j) {
            float mn, sp;
            leaky_upd(zp[j], m[j], be[j], th[j], mn, sp);
            m[j] = mn;
            b |= (sp != 0.0f ? 1u : 0u) << j;
        }
        spk0b[(size_t)s * 65536 + bidx] = (unsigned char)b;
    }
    #pragma unroll
    for (int j = 0; j < 8; ++j) mem0_g[i0 + j] = m[j];
}

// ---------------- grid barrier ----------------------------------------------
__device__ __forceinline__ void gridbar(int* flags, int* gen, int target) {
    __syncthreads();
    if (threadIdx.x == 0) {
        __builtin_amdgcn_fence(__ATOMIC_RELEASE, "agent");
        __hip_atomic_store(&flags[blockIdx.x], target, __ATOMIC_RELAXED, __HIP_MEMORY_SCOPE_AGENT);
    }
    if (blockIdx.x == 0) {
        if (threadIdx.x < 64) {
            const int l = threadIdx.x;
            for (;;) {
                int v0 = __hip_atomic_load(&flags[l],       __ATOMIC_RELAXED, __HIP_MEMORY_SCOPE_AGENT);
                int v1 = __hip_atomic_load(&flags[l + 64],  __ATOMIC_RELAXED, __HIP_MEMORY_SCOPE_AGENT);
                int v2 = __hip_atomic_load(&flags[l + 128], __ATOMIC_RELAXED, __HIP_MEMORY_SCOPE_AGENT);
                int mn = min(min(v0, v1), v2);
                if (__all(mn >= target)) break;
                __builtin_amdgcn_s_sleep(1);
            }
        }
        __syncthreads();
        if (threadIdx.x == 0) {
            __builtin_amdgcn_fence(__ATOMIC_ACQ_REL, "agent");
            __hip_atomic_store(gen, target, __ATOMIC_RELAXED, __HIP_MEMORY_SCOPE_AGENT);
        }
    } else if (threadIdx.x == 0) {
        while (__hip_atomic_load(gen, __ATOMIC_RELAXED, __HIP_MEMORY_SCOPE_AGENT) < target)
            __builtin_amdgcn_s_sleep(2);
    }
    __syncthreads();
    __builtin_amdgcn_fence(__ATOMIC_ACQUIRE, "agent");
}

// ---------------- hidden-layer pipeline (persistent, bits, LUT expand) ------
// Block = one layer's 32-col x 256-row slice.  64 blocks/layer:
//   cs = (blk&63)>>1 (col-pair 0..31), rh = blk&1 (row half).
// LDS: planes 1,2 for both 16-col groups (128KB) + 16-entry nibble LUT.
// Plane 3 streamed from global (L2) with 1-kt-ahead prefetch.
__global__ __launch_bounds__(512, 1)
void snn_pipe(const unsigned int* __restrict__ spk0w,
              unsigned int* __restrict__ spk3w,
              const __bf16* __restrict__ Wt,
              const float* __restrict__ b_h,
              const float* __restrict__ beta_h,
              const float* __restrict__ thr_h,
              float* __restrict__ mem123,
              unsigned int* __restrict__ ring1,
              unsigned int* __restrict__ ring2,
              int* __restrict__ flags, int* __restrict__ gen,
              int tc)
{
    __shared__ __bf16 Wlds[4 * 32 * 512];        // 128 KB: [p*2+nt][kt][512]
    __shared__ unsigned long long lut[16];       // nibble -> 4 bf16 (8B)

    const int blk  = blockIdx.x;
    const int tid  = threadIdx.x;
    const int lane = tid & 63;
    const int w    = tid >> 6;              // 8 waves
    const int ell  = blk >> 6;
    const int cs   = (blk & 63) >> 1;       // col-pair
    const int rh   = blk & 1;               // row half

    if (tid < 16) {
        unsigned int lo = ((tid & 1) ? 0x3F80u : 0u) | ((tid & 2) ? 0x3F800000u : 0u);
        unsigned int hi = ((tid & 4) ? 0x3F80u : 0u) | ((tid & 8) ? 0x3F800000u : 0u);
        lut[tid] = ((unsigned long long)hi << 32) | lo;
    }

    // stage planes 0,1 for col groups cs*2, cs*2+1
    {
        const __bf16* Wbase = Wt + (size_t)ell * 3 * (NH * NH);
        #pragma unroll
        for (int p = 0; p < 2; ++p) {
            #pragma unroll
            for (int nt = 0; nt < 2; ++nt) {
                const bf16x8* src = reinterpret_cast<const bf16x8*>(
                    Wbase + (size_t)p * (NH * NH) + (size_t)(cs * 2 + nt) * 16384);
                bf16x8* dst = reinterpret_cast<bf16x8*>(Wlds + (p * 2 + nt) * 16384);
                for (int i = tid; i < 2048; i += 512) dst[i] = src[i];
            }
        }
    }
    const __bf16* W3 = Wt + (size_t)ell * 3 * (NH * NH) + 2 * (size_t)(NH * NH);

    const int c   = lane & 15;
    const int r0  = (lane >> 4) * 4;
    const int row = lane & 15;
    const int sh  = (lane >> 4) * 8;

    float* memg = mem123 + (size_t)ell * (NB * NH);
    float bi[2], be[2], th[2];
    #pragma unroll
    for (int nt = 0; nt < 2; ++nt) {
        const int n = cs * 32 + nt * 16 + c;
        bi[nt] = b_h[ell * NH + n];
        be[nt] = beta_h[(ell + 1) * NH + n];
        th[nt] = thr_h[(ell + 1) * NH + n];
    }

    float memr[2][2][4];   // [i][nt][r]
    #pragma unroll
    for (int i = 0; i < 2; ++i)
        #pragma unroll
        for (int nt = 0; nt < 2; ++nt)
            #pragma unroll
            for (int r = 0; r < 4; ++r)
                memr[i][nt][r] = memg[(size_t)(rh * 256 + (w * 2 + i) * 16 + r0 + r) * NH
                                      + cs * 32 + nt * 16 + c];

    const int G = (tc + NT - 1) / NT;
    __syncthreads();

    for (int p = 0; p < G + 2; ++p) {
        const int g = p - ell;
        if (g >= 0 && g < G) {
            const int sbase = g * NT;
            const int send  = (sbase + NT < tc) ? sbase + NT : tc;
            const int slot0 = (g & 1) * NT;
            for (int s = sbase; s < send; s += 2) {
                const int sl = slot0 + (s - sbase);
                const unsigned int* X0w = (ell == 0) ? spk0w + (size_t)s * BITFRAME
                                        : ((ell == 1) ? ring1 : ring2) + (size_t)sl * BITFRAME;
                unsigned short* Y0h = (unsigned short*)(
                    (ell == 2) ? spk3w + (size_t)s * BITFRAME
                               : ((ell == 0) ? ring1 : ring2) + (size_t)sl * BITFRAME);
                const bool pair = (s + 1 < send);
                const unsigned int* X1w = pair ?
                    ((ell == 0) ? spk0w + (size_t)(s + 1) * BITFRAME
                                : ((ell == 1) ? ring1 : ring2) + (size_t)(sl + 1) * BITFRAME)
                    : X0w;
                unsigned short* Y1h = pair ? (unsigned short*)(
                    (ell == 2) ? spk3w + (size_t)(s + 1) * BITFRAME
                               : ((ell == 0) ? ring1 : ring2) + (size_t)(sl + 1) * BITFRAME)
                    : Y0h;

                f32x4 acc[2][2][2] = {};   // [step][i][nt]
                unsigned int bw0[2], bw1[2];
                bf16x8 w3f[2];
                #pragma unroll
                for (int i = 0; i < 2; ++i) {
                    const int wi = ((rh * 16 + w * 2 + i) * 32 + 0) * 16 + row;
                    bw0[i] = X0w[wi];
                    bw1[i] = X1w[wi];
                }
                #pragma unroll
                for (int nt = 0; nt < 2; ++nt)
                    w3f[nt] = *reinterpret_cast<const bf16x8*>(
                        W3 + (size_t)(cs * 2 + nt) * 16384 + 0 * 512 + lane * 8);

                for (int kt = 0; kt < 32; ++kt) {
                    unsigned int nb0[2], nb1[2];
                    bf16x8 nw3[2];
                    if (kt < 31) {
                        #pragma unroll
                        for (int i = 0; i < 2; ++i) {
                            const int wi = ((rh * 16 + w * 2 + i) * 32 + kt + 1) * 16 + row;
                            nb0[i] = X0w[wi];
                            nb1[i] = X1w[wi];
                        }
                        #pragma unroll
                        for (int nt = 0; nt < 2; ++nt)
                            nw3[nt] = *reinterpret_cast<const bf16x8*>(
                                W3 + (size_t)(cs * 2 + nt) * 16384 + (size_t)(kt + 1) * 512 + lane * 8);
                    }
                    const int lo = kt * 512 + lane * 8;
                    bf16x8 b10 = *reinterpret_cast<const bf16x8*>(Wlds + 0 * 16384 + lo);
                    bf16x8 b11 = *reinterpret_cast<const bf16x8*>(Wlds + 1 * 16384 + lo);
                    bf16x8 b20 = *reinterpret_cast<const bf16x8*>(Wlds + 2 * 16384 + lo);
                    bf16x8 b21 = *reinterpret_cast<const bf16x8*>(Wlds + 3 * 16384 + lo);

                    #pragma unroll
                    for (int i = 0; i < 2; ++i) {
                        unsigned int by = (bw0[i] >> sh) & 0xffu;
                        union { unsigned long long q[2]; bf16x8 v; } a;
                        a.q[0] = lut[by & 15u];
                        a.q[1] = lut[by >> 4];
                        acc[0][i][0] = __builtin_amdgcn_mfma_f32_16x16x32_bf16(a.v, b10, acc[0][i][0], 0, 0, 0);
                        acc[0][i][1] = __builtin_amdgcn_mfma_f32_16x16x32_bf16(a.v, b11, acc[0][i][1], 0, 0, 0);
                        acc[0][i][0] = __builtin_amdgcn_mfma_f32_16x16x32_bf16(a.v, b20, acc[0][i][0], 0, 0, 0);
                        acc[0][i][1] = __builtin_amdgcn_mfma_f32_16x16x32_bf16(a.v, b21, acc[0][i][1], 0, 0, 0);
                        acc[0][i][0] = __builtin_amdgcn_mfma_f32_16x16x32_bf16(a.v, w3f[0], acc[0][i][0], 0, 0, 0);
                        acc[0][i][1] = __builtin_amdgcn_mfma_f32_16x16x32_bf16(a.v, w3f[1], acc[0][i][1], 0, 0, 0);
                    }
                    if (pair) {
                        #pragma unroll
                        for (int i = 0; i < 2; ++i) {
                            unsigned int by = (bw1[i] >> sh) & 0xffu;
                            union { unsigned long long q[2]; bf16x8 v; } a;
                            a.q[0] = lut[by & 15u];
                            a.q[1] = lut[by >> 4];
                            acc[1][i][0] = __builtin_amdgcn_mfma_f32_16x16x32_bf16(a.v, b10, acc[1][i][0], 0, 0, 0);
                            acc[1][i][1] = __builtin_amdgcn_mfma_f32_16x16x32_bf16(a.v, b11, acc[1][i][1], 0, 0, 0);
                            acc[1][i][0] = __builtin_amdgcn_mfma_f32_16x16x32_bf16(a.v, b20, acc[1][i][0], 0, 0, 0);
                            acc[1][i][1] = __builtin_amdgcn_mfma_f32_16x16x32_bf16(a.v, b21, acc[1][i][1], 0, 0, 0);
                            acc[1][i][0] = __builtin_amdgcn_mfma_f32_16x16x32_bf16(a.v, w3f[0], acc[1][i][0], 0, 0, 0);
                            acc[1][i][1] = __builtin_amdgcn_mfma_f32_16x16x32_bf16(a.v, w3f[1], acc[1][i][1], 0, 0, 0);
                        }
                    }
                    if (kt < 31) {
                        #pragma unroll
                        for (int i = 0; i < 2; ++i) { bw0[i] = nb0[i]; bw1[i] = nb1[i]; }
                        w3f[0] = nw3[0]; w3f[1] = nw3[1];
                    }
                }

                // epilogue step s
                #pragma unroll
                for (int i = 0; i < 2; ++i) {
                    #pragma unroll
                    for (int nt = 0; nt < 2; ++nt) {
                        #pragma unroll
                        for (int r = 0; r < 4; ++r) {
                            float mn, sp;
                            leaky_upd(acc[0][i][nt][r] + bi[nt], memr[i][nt][r], be[nt], th[nt], mn, sp);
                            memr[i][nt][r] = mn;
                            unsigned long long bal = __ballot(sp != 0.0f);
                            if ((lane & 15) == 0) {
                                const int rr = (lane >> 4) * 4 + r;
                                Y0h[(((rh * 16 + w * 2 + i) * 32 + cs) * 16 + rr) * 2 + nt] =
                                    (unsigned short)((bal >> ((lane >> 4) * 16)) & 0xFFFFu);
                            }
                        }
                    }
                }
                if (pair) {
                    #pragma unroll
                    for (int i = 0; i < 2; ++i) {
                        #pragma unroll
                        for (int nt = 0; nt < 2; ++nt) {
                            #pragma unroll
                            for (int r = 0; r < 4; ++r) {
                                float mn, sp;
                                leaky_upd(acc[1][i][nt][r] + bi[nt], memr[i][nt][r], be[nt], th[nt], mn, sp);
                                memr[i][nt][r] = mn;
                                unsigned long long bal = __ballot(sp != 0.0f);
                                if ((lane & 15) == 0) {
                                    const int rr = (lane >> 4) * 4 + r;
                                    Y1h[(((rh * 16 + w * 2 + i) * 32 + cs) * 16 + rr) * 2 + nt] =
                                        (unsigned short)((bal >> ((lane >> 4) * 16)) & 0xFFFFu);
                                }
                            }
                        }
                    }
                }
            }
        }
        gridbar(flags, gen, p + 1);
    }

    #pragma unroll
    for (int i = 0; i < 2; ++i)
        #pragma unroll
        for (int nt = 0; nt < 2; ++nt)
            #pragma unroll
            for (int r = 0; r < 4; ++r)
                memg[(size_t)(rh * 256 + (w * 2 + i) * 16 + r0 + r) * NH
                     + cs * 32 + nt * 16 + c] = memr[i][nt][r];
}

// ---------------- batched output GEMM over the chunk (bits in) --------------
__global__ __launch_bounds__(256)
void zout_gemm(const unsigned int* __restrict__ spk3w,
               const __bf16* __restrict__ Wo_t,
               const float* __restrict__ b_out,
               float* __restrict__ zout)
{
    const int s  = blockIdx.x >> 2;
    const int rg = blockIdx.x & 3;
    const int tid = threadIdx.x;
    const int lane = tid & 63;
    const int w = tid >> 6;
    const int row = lane & 15;
    const int sh = (lane >> 4) * 8;
    const size_t PS = (size_t)48 * NH;
    const unsigned int* Xw = spk3w + (size_t)s * BITFRAME;

    f32x4 acc[2][3] = {};
    for (int kt = 0; kt < 32; ++kt) {
        const int lo = kt * 512 + lane * 8;
        bf16x8 a[2];
        #pragma unroll
        for (int i = 0; i < 2; ++i) {
            const int gmt = rg * 8 + w * 2 + i;
            unsigned int bw = Xw[(gmt * 32 + kt) * 16 + row];
            a[i] = expand_byte((bw >> sh) & 0xffu);
        }
        #pragma unroll
        for (int nt = 0; nt < 3; ++nt) {
            const size_t bo = (size_t)nt * 16384 + lo;
            bf16x8 b1 = *reinterpret_cast<const bf16x8*>(Wo_t + bo);
            bf16x8 b2 = *reinterpret_cast<const bf16x8*>(Wo_t + PS + bo);
            bf16x8 b3 = *reinterpret_cast<const bf16x8*>(Wo_t + 2 * PS + bo);
            #pragma unroll
            for (int i = 0; i < 2; ++i) {
                acc[i][nt] = __builtin_amdgcn_mfma_f32_16x16x32_bf16(a[i], b1, acc[i][nt], 0, 0, 0);
                acc[i][nt] = __builtin_amdgcn_mfma_f32_16x16x32_bf16(a[i], b2, acc[i][nt], 0, 0, 0);
                acc[i][nt] = __builtin_amdgcn_mfma_f32_16x16x32_bf16(a[i], b3, acc[i][nt], 0, 0, 0);
            }
        }
    }

    const int cc = lane & 15, rr0 = (lane >> 4) * 4;
    #pragma unroll
    for (int nt = 0; nt < 3; ++nt) {
        const int o = nt * 16 + cc;
        if (o < NO) {
            const float bi = b_out[o];
            #pragma unroll
            for (int i = 0; i < 2; ++i) {
                #pragma unroll
                for (int r = 0; r < 4; ++r) {
                    const int b = (rg * 8 + w * 2 + i) * 16 + rr0 + r;
                    zout[((size_t)s * NB + b) * 48 + o] = acc[i][nt][r] + bi;
                }
            }
        }
    }
}

// ---------------- sequential output leaky ------------------------------------
__global__ __launch_bounds__(256)
void out_seq(const float* __restrict__ zout,
             float* __restrict__ out,
             float* __restrict__ memo_g,
             const float* __restrict__ beta_o,
             const float* __restrict__ thr_o,
             int t0, int tc)
{
    const int g = blockIdx.x * 256 + threadIdx.x;
    if (g >= NB * NO) return;
    const int b = g / NO;
    const int o = g - b * NO;
    float mem = memo_g[g];
    const float be = beta_o[o], th = thr_o[o];
    for (int s = 0; s < tc; ++s) {
        float z = zout[((size_t)s * NB + b) * 48 + o];
        float mn, sp;
        leaky_upd(z, mem, be, th, mn, sp);
        mem = mn;
        out[((size_t)(t0 + s) * NB + b) * NO + o] = sp;
    }
    memo_g[g] = mem;
}

// ---------------- launch ----------------------------------------------------
extern "C" void kernel_launch(void* const* d_in, const int* in_sizes, int n_in,
                              void* d_out, int out_size, void* d_ws, size_t ws_size,
                              hipStream_t stream) {
    const float* data   = (const float*)d_in[0];
    const float* W_in   = (const float*)d_in[1];
    const float* b_in   = (const float*)d_in[2];
    const float* W_h    = (const float*)d_in[3];
    const float* b_h    = (const float*)d_in[4];
    const float* W_out  = (const float*)d_in[5];
    const float* b_out  = (const float*)d_in[6];
    const float* beta_h = (const float*)d_in[7];
    const float* thr_h  = (const float*)d_in[8];
    const float* beta_o = (const float*)d_in[9];
    const float* thr_o  = (const float*)d_in[10];
    float* out = (float*)d_out;

    char* ws = (char*)d_ws;
    float*        mem123 = (float*)(ws + WS_MEM123);
    float*        mem0_g = (float*)(ws + WS_MEM0);
    float*        memo_g = (float*)(ws + WS_MEMO);
    int*          flags  = (int*)(ws + WS_FLAGS);
    int*          gen    = (int*)(ws + WS_GEN);
    unsigned int* ring1  = (unsigned int*)(ws + WS_SPK1);
    unsigned int* ring2  = (unsigned int*)(ws + WS_SPK2);
    __bf16*       Wt     = (__bf16*)(ws + WS_WT);
    __bf16*       Wi_t   = (__bf16*)(ws + WS_WIT);
    __bf16*       Wo_t   = (__bf16*)(ws + WS_WOT);

    size_t avail = (ws_size > WS_DYN) ? (ws_size - WS_DYN) / STEP_BYTES : 1;
    int Tc = (int)(avail < 1 ? 1 : (avail > TT ? TT : avail));

    float*         zout  = (float*)(ws + WS_DYN);
    unsigned char* spk0b = (unsigned char*)(ws + WS_DYN + (size_t)Tc * 98304u);
    char*          unionb = ws + WS_DYN + (size_t)Tc * (98304u + 65536u);
    float*         Z0    = (float*)unionb;
    unsigned int*  spk3w = (unsigned int*)unionb;

    hipMemsetAsync(ws, 0, WS_FLAGS, stream);
    split_weights<<<dim3(1536), dim3(256), 0, stream>>>(W_h, Wt);
    split_win<<<dim3(256), dim3(256), 0, stream>>>(W_in, Wi_t);
    split_wout<<<dim3(24), dim3(256), 0, stream>>>(W_out, Wo_t);

    for (int t0c = 0; t0c < TT; t0c += Tc) {
        const int tcc = (TT - t0c < Tc) ? (TT - t0c) : Tc;
        z0_gemm<<<dim3(NH / 64, tcc * (NB / 64)), dim3(256), 0, stream>>>(
            data + (size_t)t0c * NB * NI, Wi_t, b_in, Z0);
        leaky0_seq<<<dim3(256), dim3(256), 0, stream>>>(
            Z0, spk0b, mem0_g, beta_h, thr_h, tcc);
        hipMemsetAsync(ws + WS_FLAGS, 0, 1280, stream);
        snn_pipe<<<dim3(NBLK_P), dim3(512), 0, stream>>>(
            (const unsigned int*)spk0b, spk3w, Wt, b_h, beta_h, thr_h,
            mem123, ring1, ring2, flags, gen, tcc);
        zout_gemm<<<dim3(tcc * 4), dim3(256), 0, stream>>>(
            spk3w, Wo_t, b_out, zout);
        out_seq<<<dim3((NB * NO + 255) / 256), dim3(256), 0, stream>>>(
            zout, out, memo_g, beta_o, thr_o, t0c, tcc);
    }
}

// Round 10
// 1849.677 us; speedup vs baseline: 10.5960x; 1.0297x over previous
//
#include <hip/hip_runtime.h>
#include <hip/hip_bf16.h>

// SNN, 5 layers, T=100, B=512.  R10: 4-stage 256-block persistent pipeline.
//  Phase p:  Z:leaky0(g=p) | L1(g=p-1) | L2(p-2) | L3(p-3) | out(p-4)
//  - blocks 0..191: hidden layers (32col x 256row, planes 1+2 in LDS, plane 3
//    streamed, LUT bit->bf16 expand, QUAD-step K-loop batching).
//  - blocks 192..255: stage Z = leaky0 (mem in regs, 16 elems/thread, reads
//    Z0) ; blocks 192..223 waves 0..2 also do output layer (zout MFMA +
//    in-register out-leaky, writes d_out).  All spikes = bit frames in rings.
//  Prelude: weight splits + z0_gemm only.

#define NB 512
#define NH 1024
#define NI 512
#define NO 35
#define TT 100
#define NT 8
#define BITFRAME 16384   // u32 words per 512x1024 bit frame (64KB)

typedef __bf16 bf16x8 __attribute__((ext_vector_type(8)));
typedef float f32x4 __attribute__((ext_vector_type(4)));

__device__ __forceinline__ size_t tiled_off(int row, int k, int KT) {
    return ((size_t)((row >> 4) * KT + (k >> 5)) * 64
            + (row & 15) + (((k >> 3) & 3) << 4)) * 8 + (k & 7);
}

__device__ __forceinline__ void leaky_upd(float zin, float mprev, float be, float th,
                                          float& mnew, float& spk) {
    float rs = (mprev - th > 0.0f) ? th : 0.0f;
    float bc = fminf(fmaxf(be, 0.0f), 1.0f);
    mnew = bc * mprev + zin - rs;
    spk  = (mnew - th > 0.0f) ? 1.0f : 0.0f;
}

// ---------------- ws layout (bytes) ----------------
#define WS_MEM123   0u           // 6,291,456
#define WS_MEM0     6291456u     // 2,097,152 (tiled-linear fp32)
#define WS_MEMO     8388608u     // 98,304 (71,680 used)
#define WS_FLAGS    8486912u     // 1,024
#define WS_GEN      8487936u     // 256
#define WS_RING0    8488192u     // 16 frames = 1,048,576
#define WS_RING1    9536768u
#define WS_RING2    10585344u
#define WS_RING3    11633920u
#define WS_WT       12682496u    // 18,874,368
#define WS_WIT      31556864u    // 3,145,728
#define WS_WOT      34702592u    // 294,912
#define WS_Z0       34997504u    // Tc * 2,097,152
#define STEP_BYTES  2097152u

// ---------------- weight splits ----------------
__global__ __launch_bounds__(256)
void split_weights(const float* __restrict__ W_h, __bf16* __restrict__ Wt) {
    const int id = blockIdx.x * 256 + threadIdx.x;
    const int layer = id >> 17;
    const int rem = id & 131071;
    const int n = rem >> 7;
    const int k0 = (rem & 127) << 3;
    const float* src = W_h + ((size_t)layer * NH + n) * NH + k0;
    __bf16* dst = Wt + (size_t)layer * 3 * NH * NH;
    const size_t PS = (size_t)NH * NH;
    const size_t off = tiled_off(n, k0, 32);
    bf16x8 p1, p2, p3;
    #pragma unroll
    for (int j = 0; j < 8; ++j) {
        float w = src[j];
        __bf16 a = (__bf16)w;  float r1 = w - (float)a;
        __bf16 b = (__bf16)r1; float r2 = r1 - (float)b;
        __bf16 c = (__bf16)r2;
        p1[j] = a; p2[j] = b; p3[j] = c;
    }
    *reinterpret_cast<bf16x8*>(dst + 0 * PS + off) = p1;
    *reinterpret_cast<bf16x8*>(dst + 1 * PS + off) = p2;
    *reinterpret_cast<bf16x8*>(dst + 2 * PS + off) = p3;
}

__global__ __launch_bounds__(256)
void split_win(const float* __restrict__ W_in, __bf16* __restrict__ Wi_t) {
    const int id = blockIdx.x * 256 + threadIdx.x;
    const int n = id >> 6;
    const int k0 = (id & 63) << 3;
    const float* src = W_in + (size_t)n * NI + k0;
    const size_t PS = (size_t)NH * NI;
    const size_t off = tiled_off(n, k0, 16);
    bf16x8 p1, p2, p3;
    #pragma unroll
    for (int j = 0; j < 8; ++j) {
        float w = src[j];
        __bf16 a = (__bf16)w;  float r1 = w - (float)a;
        __bf16 b = (__bf16)r1; float r2 = r1 - (float)b;
        __bf16 c = (__bf16)r2;
        p1[j] = a; p2[j] = b; p3[j] = c;
    }
    *reinterpret_cast<bf16x8*>(Wi_t + 0 * PS + off) = p1;
    *reinterpret_cast<bf16x8*>(Wi_t + 1 * PS + off) = p2;
    *reinterpret_cast<bf16x8*>(Wi_t + 2 * PS + off) = p3;
}

__global__ __launch_bounds__(256)
void split_wout(const float* __restrict__ W_out, __bf16* __restrict__ Wo_t) {
    const int id = blockIdx.x * 256 + threadIdx.x;
    if (id >= 48 * 128) return;
    const int o = id >> 7;
    const int k0 = (id & 127) << 3;
    const size_t PS = (size_t)48 * NH;
    const size_t off = tiled_off(o, k0, 32);
    bf16x8 p1 = {}, p2 = {}, p3 = {};
    if (o < NO) {
        const float* src = W_out + (size_t)o * NH + k0;
        #pragma unroll
        for (int j = 0; j < 8; ++j) {
            float w = src[j];
            __bf16 a = (__bf16)w;  float r1 = w - (float)a;
            __bf16 b = (__bf16)r1; float r2 = r1 - (float)b;
            __bf16 c = (__bf16)r2;
            p1[j] = a; p2[j] = b; p3[j] = c;
        }
    }
    *reinterpret_cast<bf16x8*>(Wo_t + 0 * PS + off) = p1;
    *reinterpret_cast<bf16x8*>(Wo_t + 1 * PS + off) = p2;
    *reinterpret_cast<bf16x8*>(Wo_t + 2 * PS + off) = p3;
}

// ---------------- Z0 = data @ W_in^T + b_in (6-term bf16 MFMA) --------------
__global__ __launch_bounds__(256)
void z0_gemm(const float* __restrict__ X,
             const __bf16* __restrict__ Wi_t,
             const float* __restrict__ bias,
             float* __restrict__ Z0)
{
    const int tid = threadIdx.x;
    const int lane = tid & 63;
    const int w = tid >> 6;
    const int wm = w >> 1, wn = w & 1;
    const int m_base = blockIdx.y * 64 + wm * 32;
    const int n_base = blockIdx.x * 64 + wn * 32;
    const size_t PS = (size_t)NH * NI;

    f32x4 acc[2][2] = {};
    bf16x8 a1[2], a2[2], a3[2];

    for (int kt = 0; kt < 16; ++kt) {
        #pragma unroll
        for (int mt = 0; mt < 2; ++mt) {
            const int row = m_base + mt * 16 + (lane & 15);
            const float* src = X + (size_t)row * NI + kt * 32 + ((lane >> 4) << 3);
            float4 v0 = *reinterpret_cast<const float4*>(src);
            float4 v1 = *reinterpret_cast<const float4*>(src + 4);
            float xv[8] = {v0.x, v0.y, v0.z, v0.w, v1.x, v1.y, v1.z, v1.w};
            #pragma unroll
            for (int j = 0; j < 8; ++j) {
                float x = xv[j];
                __bf16 h1 = (__bf16)x;  float r1 = x - (float)h1;
                __bf16 h2 = (__bf16)r1; float r2 = r1 - (float)h2;
                __bf16 h3 = (__bf16)r2;
                a1[mt][j] = h1; a2[mt][j] = h2; a3[mt][j] = h3;
            }
        }
        #pragma unroll
        for (int nt = 0; nt < 2; ++nt) {
            const size_t bo = ((size_t)(((n_base >> 4) + nt) * 16 + kt) * 64 + lane) * 8;
            bf16x8 b1 = *reinterpret_cast<const bf16x8*>(Wi_t + bo);
            bf16x8 b2 = *reinterpret_cast<const bf16x8*>(Wi_t + PS + bo);
            bf16x8 b3 = *reinterpret_cast<const bf16x8*>(Wi_t + 2 * PS + bo);
            #pragma unroll
            for (int mt = 0; mt < 2; ++mt) {
                f32x4 A = acc[mt][nt];
                A = __builtin_amdgcn_mfma_f32_16x16x32_bf16(a1[mt], b1, A, 0, 0, 0);
                A = __builtin_amdgcn_mfma_f32_16x16x32_bf16(a1[mt], b2, A, 0, 0, 0);
                A = __builtin_amdgcn_mfma_f32_16x16x32_bf16(a2[mt], b1, A, 0, 0, 0);
                A = __builtin_amdgcn_mfma_f32_16x16x32_bf16(a2[mt], b2, A, 0, 0, 0);
                A = __builtin_amdgcn_mfma_f32_16x16x32_bf16(a1[mt], b3, A, 0, 0, 0);
                A = __builtin_amdgcn_mfma_f32_16x16x32_bf16(a3[mt], b1, A, 0, 0, 0);
                acc[mt][nt] = A;
            }
        }
    }

    const int c = lane & 15;
    const int r0 = (lane >> 4) * 4;
    #pragma unroll
    for (int nt = 0; nt < 2; ++nt) {
        const int n = n_base + nt * 16 + c;
        const float bi = bias[n];
        #pragma unroll
        for (int mt = 0; mt < 2; ++mt) {
            #pragma unroll
            for (int r = 0; r < 4; ++r) {
                const int m = m_base + mt * 16 + r0 + r;
                const int tl = m >> 9, b = m & 511;
                Z0[(size_t)tl * (NB * NH) + tiled_off(b, n, 32)] = acc[mt][nt][r] + bi;
            }
        }
    }
}

// ---------------- grid barrier (256 blocks) ----------------------------------
__device__ __forceinline__ void gridbar(int* flags, int* gen, int target) {
    __syncthreads();
    if (threadIdx.x == 0) {
        __builtin_amdgcn_fence(__ATOMIC_RELEASE, "agent");
        __hip_atomic_store(&flags[blockIdx.x], target, __ATOMIC_RELAXED, __HIP_MEMORY_SCOPE_AGENT);
    }
    if (blockIdx.x == 0) {
        if (threadIdx.x < 64) {
            const int l = threadIdx.x;
            for (;;) {
                int v0 = __hip_atomic_load(&flags[l],       __ATOMIC_RELAXED, __HIP_MEMORY_SCOPE_AGENT);
                int v1 = __hip_atomic_load(&flags[l + 64],  __ATOMIC_RELAXED, __HIP_MEMORY_SCOPE_AGENT);
                int v2 = __hip_atomic_load(&flags[l + 128], __ATOMIC_RELAXED, __HIP_MEMORY_SCOPE_AGENT);
                int v3 = __hip_atomic_load(&flags[l + 192], __ATOMIC_RELAXED, __HIP_MEMORY_SCOPE_AGENT);
                int mn = min(min(v0, v1), min(v2, v3));
                if (__all(mn >= target)) break;
                __builtin_amdgcn_s_sleep(1);
            }
        }
        __syncthreads();
        if (threadIdx.x == 0) {
            __builtin_amdgcn_fence(__ATOMIC_ACQ_REL, "agent");
            __hip_atomic_store(gen, target, __ATOMIC_RELAXED, __HIP_MEMORY_SCOPE_AGENT);
        }
    } else if (threadIdx.x == 0) {
        while (__hip_atomic_load(gen, __ATOMIC_RELAXED, __HIP_MEMORY_SCOPE_AGENT) < target)
            __builtin_amdgcn_s_sleep(2);
    }
    __syncthreads();
    __builtin_amdgcn_fence(__ATOMIC_ACQUIRE, "agent");
}

// ---------------- hidden NS-step body ----------------------------------------
template<int NS>
__device__ __forceinline__ void hidden_run(
    const unsigned int* const* Xp, unsigned short* const* Yp,
    const __bf16* Wldsp, const unsigned long long* lutp, const __bf16* W3,
    int cs, int rh, int w, int lane,
    float (&memr)[2][2][4], const float (&bi)[2], const float (&be)[2],
    const float (&th)[2])
{
    const int row = lane & 15;
    const int sh = (lane >> 4) * 8;
    f32x4 acc[NS][2][2] = {};
    unsigned int bw[NS][2];
    bf16x8 w3f[2];

    #pragma unroll
    for (int q = 0; q < NS; ++q)
        #pragma unroll
        for (int i = 0; i < 2; ++i)
            bw[q][i] = Xp[q][((rh * 16 + w * 2 + i) * 32) * 16 + row];
    #pragma unroll
    for (int nt = 0; nt < 2; ++nt)
        w3f[nt] = *reinterpret_cast<const bf16x8*>(W3 + (size_t)(cs * 2 + nt) * 16384 + lane * 8);

    for (int kt = 0; kt < 32; ++kt) {
        unsigned int nb[NS][2];
        bf16x8 nw3[2];
        if (kt < 31) {
            #pragma unroll
            for (int q = 0; q < NS; ++q)
                #pragma unroll
                for (int i = 0; i < 2; ++i)
                    nb[q][i] = Xp[q][((rh * 16 + w * 2 + i) * 32 + kt + 1) * 16 + row];
            #pragma unroll
            for (int nt = 0; nt < 2; ++nt)
                nw3[nt] = *reinterpret_cast<const bf16x8*>(
                    W3 + (size_t)(cs * 2 + nt) * 16384 + (size_t)(kt + 1) * 512 + lane * 8);
        }
        const int lo = kt * 512 + lane * 8;
        bf16x8 b10 = *reinterpret_cast<const bf16x8*>(Wldsp + 0 * 16384 + lo);
        bf16x8 b11 = *reinterpret_cast<const bf16x8*>(Wldsp + 1 * 16384 + lo);
        bf16x8 b20 = *reinterpret_cast<const bf16x8*>(Wldsp + 2 * 16384 + lo);
        bf16x8 b21 = *reinterpret_cast<const bf16x8*>(Wldsp + 3 * 16384 + lo);

        #pragma unroll
        for (int q = 0; q < NS; ++q) {
            #pragma unroll
            for (int i = 0; i < 2; ++i) {
                unsigned int by = (bw[q][i] >> sh) & 0xffu;
                union { unsigned long long u[2]; bf16x8 v; } a;
                a.u[0] = lutp[by & 15u];
                a.u[1] = lutp[by >> 4];
                acc[q][i][0] = __builtin_amdgcn_mfma_f32_16x16x32_bf16(a.v, b10, acc[q][i][0], 0, 0, 0);
                acc[q][i][1] = __builtin_amdgcn_mfma_f32_16x16x32_bf16(a.v, b11, acc[q][i][1], 0, 0, 0);
                acc[q][i][0] = __builtin_amdgcn_mfma_f32_16x16x32_bf16(a.v, b20, acc[q][i][0], 0, 0, 0);
                acc[q][i][1] = __builtin_amdgcn_mfma_f32_16x16x32_bf16(a.v, b21, acc[q][i][1], 0, 0, 0);
                acc[q][i][0] = __builtin_amdgcn_mfma_f32_16x16x32_bf16(a.v, w3f[0], acc[q][i][0], 0, 0, 0);
                acc[q][i][1] = __builtin_amdgcn_mfma_f32_16x16x32_bf16(a.v, w3f[1], acc[q][i][1], 0, 0, 0);
            }
        }
        if (kt < 31) {
            #pragma unroll
            for (int q = 0; q < NS; ++q) { bw[q][0] = nb[q][0]; bw[q][1] = nb[q][1]; }
            w3f[0] = nw3[0]; w3f[1] = nw3[1];
        }
    }

    #pragma unroll
    for (int q = 0; q < NS; ++q) {
        #pragma unroll
        for (int i = 0; i < 2; ++i) {
            #pragma unroll
            for (int nt = 0; nt < 2; ++nt) {
                #pragma unroll
                for (int r = 0; r < 4; ++r) {
                    float mn, sp;
                    leaky_upd(acc[q][i][nt][r] + bi[nt], memr[i][nt][r], be[nt], th[nt], mn, sp);
                    memr[i][nt][r] = mn;
                    unsigned long long bal = __ballot(sp != 0.0f);
                    if ((lane & 15) == 0) {
                        const int rr = (lane >> 4) * 4 + r;
                        Yp[q][(((rh * 16 + w * 2 + i) * 32 + cs) * 16 + rr) * 2 + nt] =
                            (unsigned short)((bal >> ((lane >> 4) * 16)) & 0xFFFFu);
                    }
                }
            }
        }
    }
}

// ---------------- the 4-stage persistent pipeline ----------------------------
__global__ __launch_bounds__(512, 1)
void snn_pipe(const float* __restrict__ Z0,
              const __bf16* __restrict__ Wt,
              const __bf16* __restrict__ Wo_t,
              const float* __restrict__ b_h,
              const float* __restrict__ b_out,
              const float* __restrict__ beta_h,
              const float* __restrict__ thr_h,
              const float* __restrict__ beta_o,
              const float* __restrict__ thr_o,
              float* __restrict__ mem123,
              float* __restrict__ mem0_g,
              float* __restrict__ memo_g,
              unsigned int* __restrict__ ring0, unsigned int* __restrict__ ring1,
              unsigned int* __restrict__ ring2, unsigned int* __restrict__ ring3,
              float* __restrict__ out,
              int* __restrict__ flags, int* __restrict__ gen,
              int t0, int tc)
{
    __shared__ __bf16 Wlds[4 * 32 * 512];        // 128 KB
    __shared__ unsigned long long lut[16];

    const int blk  = blockIdx.x;
    const int tid  = threadIdx.x;
    const int lane = tid & 63;
    const int w    = tid >> 6;

    if (tid < 16) {
        unsigned int lo = ((tid & 1) ? 0x3F80u : 0u) | ((tid & 2) ? 0x3F800000u : 0u);
        unsigned int hi = ((tid & 4) ? 0x3F80u : 0u) | ((tid & 8) ? 0x3F800000u : 0u);
        lut[tid] = ((unsigned long long)hi << 32) | lo;
    }

    const int G = (tc + NT - 1) / NT;

    if (blk < 192) {
        // ================= hidden layers =================
        const int ell = blk >> 6;
        const int cs  = (blk & 63) >> 1;
        const int rh  = blk & 1;
        {
            const __bf16* Wbase = Wt + (size_t)ell * 3 * (NH * NH);
            #pragma unroll
            for (int p = 0; p < 2; ++p)
                #pragma unroll
                for (int nt = 0; nt < 2; ++nt) {
                    const bf16x8* src = reinterpret_cast<const bf16x8*>(
                        Wbase + (size_t)p * (NH * NH) + (size_t)(cs * 2 + nt) * 16384);
                    bf16x8* dst = reinterpret_cast<bf16x8*>(Wlds + (p * 2 + nt) * 16384);
                    for (int i = tid; i < 2048; i += 512) dst[i] = src[i];
                }
        }
        const __bf16* W3 = Wt + (size_t)ell * 3 * (NH * NH) + 2 * (size_t)(NH * NH);

        const int c = lane & 15;
        const int r0v = (lane >> 4) * 4;
        float* memg = mem123 + (size_t)ell * (NB * NH);
        float bi[2], be[2], th[2];
        #pragma unroll
        for (int nt = 0; nt < 2; ++nt) {
            const int n = cs * 32 + nt * 16 + c;
            bi[nt] = b_h[ell * NH + n];
            be[nt] = beta_h[(ell + 1) * NH + n];
            th[nt] = thr_h[(ell + 1) * NH + n];
        }
        float memr[2][2][4];
        #pragma unroll
        for (int i = 0; i < 2; ++i)
            #pragma unroll
            for (int nt = 0; nt < 2; ++nt)
                #pragma unroll
                for (int r = 0; r < 4; ++r)
                    memr[i][nt][r] = memg[(size_t)(rh * 256 + (w * 2 + i) * 16 + r0v + r) * NH
                                          + cs * 32 + nt * 16 + c];

        const unsigned int* rin = (ell == 0) ? ring0 : (ell == 1) ? ring1 : ring2;
        unsigned int* rout      = (ell == 0) ? ring1 : (ell == 1) ? ring2 : ring3;

        __syncthreads();

        for (int p = 0; p < G + 4; ++p) {
            const int g = p - 1 - ell;
            if (g >= 0 && g < G) {
                const int sbase = g * NT;
                const int send  = (sbase + NT < tc) ? sbase + NT : tc;
                const int slot0 = (g & 1) * NT;
                int s = sbase;
                while (s < send) {
                    const int base = slot0 + (s - sbase);
                    const unsigned int* Xp[4];
                    unsigned short* Yp[4];
                    if (send - s >= 4) {
                        #pragma unroll
                        for (int q = 0; q < 4; ++q) {
                            Xp[q] = rin + (size_t)(base + q) * BITFRAME;
                            Yp[q] = (unsigned short*)(rout + (size_t)(base + q) * BITFRAME);
                        }
                        hidden_run<4>(Xp, Yp, Wlds, lut, W3, cs, rh, w, lane, memr, bi, be, th);
                        s += 4;
                    } else {
                        Xp[0] = rin + (size_t)base * BITFRAME;
                        Yp[0] = (unsigned short*)(rout + (size_t)base * BITFRAME);
                        hidden_run<1>(Xp, Yp, Wlds, lut, W3, cs, rh, w, lane, memr, bi, be, th);
                        s += 1;
                    }
                }
            }
            gridbar(flags, gen, p + 1);
        }

        #pragma unroll
        for (int i = 0; i < 2; ++i)
            #pragma unroll
            for (int nt = 0; nt < 2; ++nt)
                #pragma unroll
                for (int r = 0; r < 4; ++r)
                    memg[(size_t)(rh * 256 + (w * 2 + i) * 16 + r0v + r) * NH
                         + cs * 32 + nt * 16 + c] = memr[i][nt][r];
    } else {
        // ================= stage Z: leaky0 + output layer =================
        const int zt   = (blk - 192) * 512 + tid;   // 0..32767, owns halfword zt
        const int wi   = zt >> 1;
        const int byt0 = (zt & 1) * 2;
        const int mtb  = wi >> 9;
        const int ktb  = (wi >> 4) & 31;
        const int rowb = wi & 15;
        const int i0   = (mtb * 32 + ktb) * 512 + rowb * 8 + byt0 * 128;
        const int n8   = ktb * 32 + byt0 * 8;

        float m0[16], be0[16], th0[16];
        #pragma unroll
        for (int j = 0; j < 8; ++j) {
            m0[j]      = mem0_g[i0 + j];
            m0[8 + j]  = mem0_g[i0 + 128 + j];
            be0[j]     = beta_h[n8 + j];
            be0[8 + j] = beta_h[n8 + 8 + j];
            th0[j]     = thr_h[n8 + j];
            th0[8 + j] = thr_h[n8 + 8 + j];
        }

        const bool outw = (blk < 224) && (w < 3);
        const int omt = blk - 192;               // 0..31 row tile (blocks 192..223)
        const int ont = w;                       // 0..2 col tile
        const int c = lane & 15, r0v = (lane >> 4) * 4;
        const int row = lane & 15, sh2 = (lane >> 4) * 8;
        const int oo = ont * 16 + c;
        const size_t OPS = (size_t)48 * NH;
        float mo[4] = {0.f, 0.f, 0.f, 0.f};
        float obi = 0.f, obe = 0.f, oth = 1.f;
        if (outw && oo < NO) {
            obi = b_out[oo]; obe = beta_o[oo]; oth = thr_o[oo];
            #pragma unroll
            for (int r = 0; r < 4; ++r) mo[r] = memo_g[(omt * 16 + r0v + r) * NO + oo];
        }

        __syncthreads();

        for (int p = 0; p < G + 4; ++p) {
            if (p < G) {
                const int sbase = p * NT;
                const int send  = (sbase + NT < tc) ? sbase + NT : tc;
                const int slot0 = (p & 1) * NT;
                for (int s = sbase; s < send; ++s) {
                    const float* zs = Z0 + (size_t)s * (NB * NH);
                    unsigned short* dsth =
                        (unsigned short*)(ring0 + (size_t)(slot0 + s - sbase) * BITFRAME);
                    float4 za = *reinterpret_cast<const float4*>(zs + i0);
                    float4 zb = *reinterpret_cast<const float4*>(zs + i0 + 4);
                    float4 zc = *reinterpret_cast<const float4*>(zs + i0 + 128);
                    float4 zd = *reinterpret_cast<const float4*>(zs + i0 + 132);
                    float zv[16] = {za.x, za.y, za.z, za.w, zb.x, zb.y, zb.z, zb.w,
                                    zc.x, zc.y, zc.z, zc.w, zd.x, zd.y, zd.z, zd.w};
                    unsigned int bits = 0;
                    #pragma unroll
                    for (int j = 0; j < 16; ++j) {
                        float mn, sp;
                        leaky_upd(zv[j], m0[j], be0[j], th0[j], mn, sp);
                        m0[j] = mn;
                        bits |= (sp != 0.0f ? 1u : 0u) << j;
                    }
                    dsth[zt] = (unsigned short)bits;
                }
            }
            if (outw) {
                const int go = p - 4;
                if (go >= 0 && go < G) {
                    const int sbase = go * NT;
                    const int send  = (sbase + NT < tc) ? sbase + NT : tc;
                    const int slot0 = (go & 1) * NT;
                    for (int s = sbase; s < send; ++s) {
                        const unsigned int* Xw =
                            ring3 + (size_t)(slot0 + s - sbase) * BITFRAME;
                        f32x4 acc = {};
                        for (int kt = 0; kt < 32; ++kt) {
                            unsigned int by = (Xw[(omt * 32 + kt) * 16 + row] >> sh2) & 0xffu;
                            union { unsigned long long u[2]; bf16x8 v; } a;
                            a.u[0] = lut[by & 15u];
                            a.u[1] = lut[by >> 4];
                            const size_t bo = ((size_t)(ont * 32 + kt) * 64 + lane) * 8;
                            bf16x8 q1 = *reinterpret_cast<const bf16x8*>(Wo_t + bo);
                            bf16x8 q2 = *reinterpret_cast<const bf16x8*>(Wo_t + OPS + bo);
                            bf16x8 q3 = *reinterpret_cast<const bf16x8*>(Wo_t + 2 * OPS + bo);
                            acc = __builtin_amdgcn_mfma_f32_16x16x32_bf16(a.v, q1, acc, 0, 0, 0);
                            acc = __builtin_amdgcn_mfma_f32_16x16x32_bf16(a.v, q2, acc, 0, 0, 0);
                            acc = __builtin_amdgcn_mfma_f32_16x16x32_bf16(a.v, q3, acc, 0, 0, 0);
                        }
                        if (oo < NO) {
                            #pragma unroll
                            for (int r = 0; r < 4; ++r) {
                                float mn, sp;
                                leaky_upd(acc[r] + obi, mo[r], obe, oth, mn, sp);
                                mo[r] = mn;
                                out[((size_t)(t0 + s) * NB + omt * 16 + r0v + r) * NO + oo] = sp;
                            }
                        }
                    }
                }
            }
            gridbar(flags, gen, p + 1);
        }

        #pragma unroll
        for (int j = 0; j < 8; ++j) {
            mem0_g[i0 + j]       = m0[j];
            mem0_g[i0 + 128 + j] = m0[8 + j];
        }
        if (outw && oo < NO) {
            #pragma unroll
            for (int r = 0; r < 4; ++r) memo_g[(omt * 16 + r0v + r) * NO + oo] = mo[r];
        }
    }
}

// ---------------- launch ----------------------------------------------------
extern "C" void kernel_launch(void* const* d_in, const int* in_sizes, int n_in,
                              void* d_out, int out_size, void* d_ws, size_t ws_size,
                              hipStream_t stream) {
    const float* data   = (const float*)d_in[0];
    const float* W_in   = (const float*)d_in[1];
    const float* b_in   = (const float*)d_in[2];
    const float* W_h    = (const float*)d_in[3];
    const float* b_h    = (const float*)d_in[4];
    const float* W_out  = (const float*)d_in[5];
    const float* b_out  = (const float*)d_in[6];
    const float* beta_h = (const float*)d_in[7];
    const float* thr_h  = (const float*)d_in[8];
    const float* beta_o = (const float*)d_in[9];
    const float* thr_o  = (const float*)d_in[10];
    float* out = (float*)d_out;

    char* ws = (char*)d_ws;
    float*        mem123 = (float*)(ws + WS_MEM123);
    float*        mem0_g = (float*)(ws + WS_MEM0);
    float*        memo_g = (float*)(ws + WS_MEMO);
    int*          flags  = (int*)(ws + WS_FLAGS);
    int*          gen    = (int*)(ws + WS_GEN);
    unsigned int* ring0  = (unsigned int*)(ws + WS_RING0);
    unsigned int* ring1  = (unsigned int*)(ws + WS_RING1);
    unsigned int* ring2  = (unsigned int*)(ws + WS_RING2);
    unsigned int* ring3  = (unsigned int*)(ws + WS_RING3);
    __bf16*       Wt     = (__bf16*)(ws + WS_WT);
    __bf16*       Wi_t   = (__bf16*)(ws + WS_WIT);
    __bf16*       Wo_t   = (__bf16*)(ws + WS_WOT);
    float*        Z0     = (float*)(ws + WS_Z0);

    size_t avail = (ws_size > WS_Z0) ? (ws_size - WS_Z0) / STEP_BYTES : 1;
    int Tc = (int)(avail < 1 ? 1 : (avail > TT ? TT : avail));

    hipMemsetAsync(ws, 0, WS_FLAGS, stream);   // mem123 + mem0 + memo
    split_weights<<<dim3(1536), dim3(256), 0, stream>>>(W_h, Wt);
    split_win<<<dim3(256), dim3(256), 0, stream>>>(W_in, Wi_t);
    split_wout<<<dim3(24), dim3(256), 0, stream>>>(W_out, Wo_t);

    for (int t0c = 0; t0c < TT; t0c += Tc) {
        const int tcc = (TT - t0c < Tc) ? (TT - t0c) : Tc;
        z0_gemm<<<dim3(NH / 64, tcc * (NB / 64)), dim3(256), 0, stream>>>(
            data + (size_t)t0c * NB * NI, Wi_t, b_in, Z0);
        hipMemsetAsync(ws + WS_FLAGS, 0, 1280, stream);   // flags + gen
        snn_pipe<<<dim3(256), dim3(512), 0, stream>>>(
            Z0, Wt, Wo_t, b_h, b_out, beta_h, thr_h, beta_o, thr_o,
            mem123, mem0_g, memo_g, ring0, ring1, ring2, ring3, out,
            flags, gen, t0c, tcc);
    }
}